// Round 1
// baseline (4441.760 us; speedup 1.0000x reference)
//
#include <hip/hip_runtime.h>
#include <cstddef>

#define B_   8
#define H_   80
#define W_   80
#define HW   6400
#define CIN_T 8

// ---------------------------------------------------------------------------
// Weight transpose: src [OC, K] -> dst [K, OC]
// ---------------------------------------------------------------------------
__global__ void wt_transpose_kernel(const float* __restrict__ src,
                                    float* __restrict__ dst, int OC, int K) {
    int idx = blockIdx.x * 256 + threadIdx.x;
    if (idx >= OC * K) return;
    int oc = idx / K, k = idx % K;
    dst[(size_t)k * OC + oc] = src[idx];
}

// ---------------------------------------------------------------------------
// Offset conv: compute 4 maps = tanh(conv3x3(x)) for offx ch{0,2}, offy ch{3,5}
// off4 layout [B][4][HW]
// ---------------------------------------------------------------------------
__global__ void off_conv_kernel(const float* __restrict__ x,
                                const float* __restrict__ wx_, const float* __restrict__ bx_,
                                const float* __restrict__ wy_, const float* __restrict__ by_,
                                float* __restrict__ off4, int CIN) {
    int idx = blockIdx.x * 256 + threadIdx.x;
    if (idx >= B_ * 4 * HW) return;
    int hw = idx % HW;
    int m  = (idx / HW) % 4;
    int b  = idx / (4 * HW);
    int h = hw / W_, w = hw % W_;
    const int chs[4] = {0, 2, 3, 5};
    int ch = chs[m];
    const float* wt; float bias;
    if (m < 2) { wt = wx_ + (size_t)ch * CIN * 9; bias = bx_[ch]; }
    else       { wt = wy_ + (size_t)ch * CIN * 9; bias = by_[ch]; }
    float acc = bias;
    const float* xb = x + (size_t)b * CIN * HW;
    for (int ci = 0; ci < CIN; ci++) {
        const float* xc = xb + (size_t)ci * HW;
        const float* wc = wt + ci * 9;
        #pragma unroll
        for (int ky = 0; ky < 3; ky++) {
            int yy = h + ky - 1;
            if (yy < 0 || yy >= H_) continue;
            #pragma unroll
            for (int kx = 0; kx < 3; kx++) {
                int xx = w + kx - 1;
                if (xx < 0 || xx >= W_) continue;
                acc += xc[yy * W_ + xx] * wc[ky * 3 + kx];
            }
        }
    }
    off4[idx] = tanhf(acc);
}

// ---------------------------------------------------------------------------
// conv3x3 + bias + SiLU.  wt is transposed weights [CIN*9][OC].
// Tile: 32 ocs x 8x8 pixels per block (256 threads; thread = 4 oc x 2 px).
// grid: (100, OC/32, B)
// ---------------------------------------------------------------------------
__global__ __launch_bounds__(256) void conv3x3_silu_kernel(
    const float* __restrict__ x, const float* __restrict__ wt,
    const float* __restrict__ bias, float* __restrict__ out, int CIN, int OC) {
    __shared__ float s_in[CIN_T][10][10];
    __shared__ float s_w[CIN_T * 9][32];
    int tile = blockIdx.x;
    int ty = (tile / 10) * 8, tx = (tile % 10) * 8;
    int ocb = blockIdx.y * 32;
    int b = blockIdx.z;
    int tid = threadIdx.x;
    int pp = tid & 31, ocg = tid >> 5;
    int p0 = pp * 2;
    int py = p0 >> 3, px = p0 & 7;   // px even
    float acc[4][2] = {};
    const float* xb = x + (size_t)b * CIN * HW;
    for (int c0 = 0; c0 < CIN; c0 += CIN_T) {
        for (int i = tid; i < CIN_T * 100; i += 256) {
            int ci = i / 100, r = (i / 10) % 10, cc = i % 10;
            int gy = ty + r - 1, gx = tx + cc - 1;
            float v = 0.f;
            if (gy >= 0 && gy < H_ && gx >= 0 && gx < W_)
                v = xb[(size_t)(c0 + ci) * HW + gy * W_ + gx];
            s_in[ci][r][cc] = v;
        }
        for (int i = tid; i < CIN_T * 9 * 32; i += 256) {
            int oc = i & 31, r = i >> 5;
            s_w[r][oc] = wt[(size_t)(c0 * 9 + r) * OC + ocb + oc];
        }
        __syncthreads();
        for (int ci = 0; ci < CIN_T; ci++) {
            #pragma unroll
            for (int ky = 0; ky < 3; ky++) {
                const float* row = &s_in[ci][py + ky][px];
                float2 a0 = *(const float2*)row;
                float2 a1 = *(const float2*)(row + 2);
                float v[4] = {a0.x, a0.y, a1.x, a1.y};
                #pragma unroll
                for (int kx = 0; kx < 3; kx++) {
                    float4 wv = *(const float4*)&s_w[ci * 9 + ky * 3 + kx][ocg * 4];
                    acc[0][0] += v[kx] * wv.x; acc[0][1] += v[kx + 1] * wv.x;
                    acc[1][0] += v[kx] * wv.y; acc[1][1] += v[kx + 1] * wv.y;
                    acc[2][0] += v[kx] * wv.z; acc[2][1] += v[kx + 1] * wv.z;
                    acc[3][0] += v[kx] * wv.w; acc[3][1] += v[kx + 1] * wv.w;
                }
            }
        }
        __syncthreads();
    }
    int gy = ty + py, gx = tx + px;
    #pragma unroll
    for (int j = 0; j < 4; j++) {
        int oc = ocb + ocg * 4 + j;
        float bb = bias[oc];
        size_t o = ((size_t)b * OC + oc) * HW + gy * W_ + gx;
        float v0 = acc[j][0] + bb;
        float v1 = acc[j][1] + bb;
        out[o]     = v0 / (1.f + expf(-v0));
        out[o + 1] = v1 / (1.f + expf(-v1));
    }
}

// ---------------------------------------------------------------------------
// Dynamic snake conv (sampling + k-conv + bias), pre-GN output.
// wt = transposed dsc weights [CIN*3][OC].  off4 [B][4][HW].
// morph0 uses maps {0,1} (bend in y), morph1 uses maps {2,3} (bend in x).
// grid: (100, OC/32, B)
// ---------------------------------------------------------------------------
__global__ __launch_bounds__(256) void dsconv_kernel(
    const float* __restrict__ x, const float* __restrict__ off4,
    const float* __restrict__ wt, const float* __restrict__ bias,
    float* __restrict__ out, int CIN, int OC, int morph) {
    __shared__ int   s_i0[3][64];
    __shared__ int   s_i1[3][64];
    __shared__ float s_wl[3][64];
    __shared__ float s_s[CIN_T][3][64];
    __shared__ float s_w[CIN_T * 3][32];
    int tile = blockIdx.x;
    int ty = (tile / 10) * 8, tx = (tile % 10) * 8;
    int ocb = blockIdx.y * 32;
    int b = blockIdx.z;
    int tid = threadIdx.x;
    if (tid < 192) {
        int k = tid / 64, p = tid % 64;
        int h = ty + (p >> 3), w = tx + (p & 7);
        float bend = 0.f;
        if (k != 1) {
            int m = (morph ? 2 : 0) + (k >> 1);
            bend = off4[((size_t)b * 4 + m) * HW + h * W_ + w];
        }
        int i0, i1; float wl;
        if (morph == 0) {
            float ys = fminf(fmaxf((float)h + bend, 0.f), 79.f);
            float y0f = floorf(ys);
            wl = ys - y0f;
            int y0 = (int)y0f;
            int y1 = min(y0 + 1, 79);
            int xk = min(max(w + k - 1, 0), 79);
            i0 = y0 * W_ + xk; i1 = y1 * W_ + xk;
        } else {
            float xs = fminf(fmaxf((float)w + bend, 0.f), 79.f);
            float x0f = floorf(xs);
            wl = xs - x0f;
            int x0 = (int)x0f;
            int x1 = min(x0 + 1, 79);
            int yk = min(max(h + k - 1, 0), 79);
            i0 = yk * W_ + x0; i1 = yk * W_ + x1;
        }
        s_i0[k][p] = i0; s_i1[k][p] = i1; s_wl[k][p] = wl;
    }
    __syncthreads();
    int pp = tid & 31, ocg = tid >> 5;
    int p0 = pp * 2;
    float acc[4][2] = {};
    for (int c0 = 0; c0 < CIN; c0 += CIN_T) {
        for (int i = tid; i < CIN_T * 192; i += 256) {
            int ci = i / 192, r = i % 192;
            int k = r >> 6, p = r & 63;
            const float* xc = x + ((size_t)b * CIN + c0 + ci) * HW;
            float wl = s_wl[k][p];
            s_s[ci][k][p] = xc[s_i0[k][p]] * (1.f - wl) + xc[s_i1[k][p]] * wl;
        }
        for (int i = tid; i < CIN_T * 3 * 32; i += 256) {
            int oc = i & 31, r = i >> 5;
            s_w[r][oc] = wt[(size_t)(c0 * 3 + r) * OC + ocb + oc];
        }
        __syncthreads();
        for (int ci = 0; ci < CIN_T; ci++) {
            #pragma unroll
            for (int k = 0; k < 3; k++) {
                float2 v = *(const float2*)&s_s[ci][k][p0];
                float4 wv = *(const float4*)&s_w[ci * 3 + k][ocg * 4];
                acc[0][0] += v.x * wv.x; acc[0][1] += v.y * wv.x;
                acc[1][0] += v.x * wv.y; acc[1][1] += v.y * wv.y;
                acc[2][0] += v.x * wv.z; acc[2][1] += v.y * wv.z;
                acc[3][0] += v.x * wv.w; acc[3][1] += v.y * wv.w;
            }
        }
        __syncthreads();
    }
    int gy = ty + (p0 >> 3), gx = tx + (p0 & 7);
    #pragma unroll
    for (int j = 0; j < 4; j++) {
        int oc = ocb + ocg * 4 + j;
        size_t o = ((size_t)b * OC + oc) * HW + gy * W_ + gx;
        out[o]     = acc[j][0] + bias[oc];
        out[o + 1] = acc[j][1] + bias[oc];
    }
}

// ---------------------------------------------------------------------------
// GroupNorm stats (groups of 4 channels): one block per (b, group)
// ---------------------------------------------------------------------------
__global__ __launch_bounds__(256) void gn_stats_kernel(
    const float* __restrict__ src, float* __restrict__ mean,
    float* __restrict__ rstd, int C) {
    int G = C >> 2;
    int bg = blockIdx.x;
    int b = bg / G, g = bg % G;
    const float* base = src + ((size_t)b * C + g * 4) * HW;
    float s = 0.f, sq = 0.f;
    for (int i = threadIdx.x; i < 4 * HW; i += 256) {
        float v = base[i];
        s += v; sq += v * v;
    }
    #pragma unroll
    for (int off = 32; off; off >>= 1) {
        s  += __shfl_down(s, off);
        sq += __shfl_down(sq, off);
    }
    __shared__ float sh[2][4];
    int wid = threadIdx.x >> 6, lane = threadIdx.x & 63;
    if (lane == 0) { sh[0][wid] = s; sh[1][wid] = sq; }
    __syncthreads();
    if (threadIdx.x == 0) {
        s  = sh[0][0] + sh[0][1] + sh[0][2] + sh[0][3];
        sq = sh[1][0] + sh[1][1] + sh[1][2] + sh[1][3];
        float m = s / (4.f * HW);
        float v = sq / (4.f * HW) - m * m;
        mean[bg] = m;
        rstd[bg] = rsqrtf(v + 1e-5f);
    }
}

// ---------------------------------------------------------------------------
// GroupNorm apply + ReLU, in place
// ---------------------------------------------------------------------------
__global__ void gn_apply_kernel(float* __restrict__ data,
                                const float* __restrict__ mean,
                                const float* __restrict__ rstd,
                                const float* __restrict__ gamma,
                                const float* __restrict__ beta, int C) {
    long idx = (long)blockIdx.x * 256 + threadIdx.x;
    long total = (long)B_ * C * HW;
    if (idx >= total) return;
    int c = (int)((idx / HW) % C);
    int b = (int)(idx / ((long)C * HW));
    int G = C >> 2;
    int g = c >> 2;
    float v = data[idx];
    v = (v - mean[b * G + g]) * rstd[b * G + g] * gamma[c] + beta[c];
    data[idx] = fmaxf(v, 0.f);
}

// ---------------------------------------------------------------------------
// Fuse 1x1 GEMM over cat([a,bx,by]) + bias + SiLU (+ optional residual)
// fwt = transposed fuse weights [3*OC][OC].  grid: (100, OC/32, B)
// ---------------------------------------------------------------------------
__global__ __launch_bounds__(256) void fuse_kernel(
    const float* __restrict__ a, const float* __restrict__ bx,
    const float* __restrict__ by, const float* __restrict__ fwt,
    const float* __restrict__ fb, const float* __restrict__ resid,
    float* __restrict__ out, int OC) {
    __shared__ float s_in[CIN_T][64];
    __shared__ float s_w[CIN_T][32];
    int hw0 = blockIdx.x * 64;
    int ocb = blockIdx.y * 32;
    int b = blockIdx.z;
    int tid = threadIdx.x;
    int pp = tid & 31, ocg = tid >> 5;
    int p0 = pp * 2;
    int K3 = 3 * OC;
    float acc[4][2] = {};
    for (int c0 = 0; c0 < K3; c0 += CIN_T) {
        for (int i = tid; i < CIN_T * 64; i += 256) {
            int ci = i >> 6, p = i & 63;
            int c = c0 + ci;
            const float* src; int cc;
            if (c < OC)           { src = a;  cc = c; }
            else if (c < 2 * OC)  { src = bx; cc = c - OC; }
            else                  { src = by; cc = c - 2 * OC; }
            s_in[ci][p] = src[((size_t)b * OC + cc) * HW + hw0 + p];
        }
        for (int i = tid; i < CIN_T * 32; i += 256) {
            int oc = i & 31, ci = i >> 5;
            s_w[ci][oc] = fwt[(size_t)(c0 + ci) * OC + ocb + oc];
        }
        __syncthreads();
        #pragma unroll
        for (int ci = 0; ci < CIN_T; ci++) {
            float2 v = *(const float2*)&s_in[ci][p0];
            float4 wv = *(const float4*)&s_w[ci][ocg * 4];
            acc[0][0] += v.x * wv.x; acc[0][1] += v.y * wv.x;
            acc[1][0] += v.x * wv.y; acc[1][1] += v.y * wv.y;
            acc[2][0] += v.x * wv.z; acc[2][1] += v.y * wv.z;
            acc[3][0] += v.x * wv.w; acc[3][1] += v.y * wv.w;
        }
        __syncthreads();
    }
    #pragma unroll
    for (int j = 0; j < 4; j++) {
        int oc = ocb + ocg * 4 + j;
        size_t o = ((size_t)b * OC + oc) * HW + hw0 + p0;
        float bb = fb[oc];
        #pragma unroll
        for (int t = 0; t < 2; t++) {
            float v = acc[j][t] + bb;
            v = v / (1.f + expf(-v));
            if (resid) v += resid[o + t];
            out[o + t] = v;
        }
    }
}

// ---------------------------------------------------------------------------
// Host-side orchestration
// ---------------------------------------------------------------------------
static void run_block(const float* xin, int CIN, int OC, const float* const* P,
                      float* abuf, float* bxb, float* byb, float* off4,
                      float* stats, float* wtc, float* wtdx, float* wtdy,
                      float* wtf, const float* resid, float* out,
                      hipStream_t stream) {
    // P: 0 conv0_w, 1 conv0_b, 2 offx_w, 3 offx_b, 4 dscx_w, 5 dscx_b,
    //    6 gnx_g, 7 gnx_b, 8 offy_w, 9 offy_b, 10 dscy_w, 11 dscy_b,
    //    12 gny_g, 13 gny_b, 14 fuse_w, 15 fuse_b
    int G = OC / 4;
    int K3 = 3 * OC;
    dim3 blk(256);
    int n;
    n = OC * CIN * 9;
    wt_transpose_kernel<<<(n + 255) / 256, blk, 0, stream>>>(P[0], wtc, OC, CIN * 9);
    n = OC * CIN * 3;
    wt_transpose_kernel<<<(n + 255) / 256, blk, 0, stream>>>(P[4], wtdx, OC, CIN * 3);
    wt_transpose_kernel<<<(n + 255) / 256, blk, 0, stream>>>(P[10], wtdy, OC, CIN * 3);
    n = OC * K3;
    wt_transpose_kernel<<<(n + 255) / 256, blk, 0, stream>>>(P[14], wtf, OC, K3);

    off_conv_kernel<<<(B_ * 4 * HW + 255) / 256, blk, 0, stream>>>(
        xin, P[2], P[3], P[8], P[9], off4, CIN);
    conv3x3_silu_kernel<<<dim3(100, OC / 32, B_), blk, 0, stream>>>(
        xin, wtc, P[1], abuf, CIN, OC);
    dsconv_kernel<<<dim3(100, OC / 32, B_), blk, 0, stream>>>(
        xin, off4, wtdx, P[5], bxb, CIN, OC, 0);
    dsconv_kernel<<<dim3(100, OC / 32, B_), blk, 0, stream>>>(
        xin, off4, wtdy, P[11], byb, CIN, OC, 1);
    gn_stats_kernel<<<B_ * G, blk, 0, stream>>>(bxb, stats, stats + 512, OC);
    gn_stats_kernel<<<B_ * G, blk, 0, stream>>>(byb, stats + 1024, stats + 1536, OC);
    long tot = (long)B_ * OC * HW;
    gn_apply_kernel<<<(tot + 255) / 256, blk, 0, stream>>>(
        bxb, stats, stats + 512, P[6], P[7], OC);
    gn_apply_kernel<<<(tot + 255) / 256, blk, 0, stream>>>(
        byb, stats + 1024, stats + 1536, P[12], P[13], OC);
    fuse_kernel<<<dim3(100, OC / 32, B_), blk, 0, stream>>>(
        abuf, bxb, byb, wtf, P[15], resid, out, OC);
}

extern "C" void kernel_launch(void* const* d_in, const int* in_sizes, int n_in,
                              void* d_out, int out_size, void* d_ws, size_t ws_size,
                              hipStream_t stream) {
    const float* x = (const float*)d_in[0];
    const float* P1[16];
    const float* P2[16];
    for (int i = 0; i < 16; i++) {
        P1[i] = (const float*)d_in[1 + i];
        P2[i] = (const float*)d_in[17 + i];
    }
    float* ws = (float*)d_ws;
    size_t o = 0;
    float* off4  = ws + o; o += (size_t)B_ * 4 * HW;        // 204800
    float* abuf  = ws + o; o += (size_t)B_ * 256 * HW;      // 13107200
    float* bxb   = ws + o; o += (size_t)B_ * 256 * HW;
    float* byb   = ws + o; o += (size_t)B_ * 256 * HW;
    float* h1    = ws + o; o += (size_t)B_ * 128 * HW;      // 6553600
    float* stats = ws + o; o += 2048;
    float* wtc   = ws + o; o += 256 * 128 * 9;              // conv0 wt (both blocks same size)
    float* wtdx  = ws + o; o += 256 * 128 * 3;
    float* wtdy  = ws + o; o += 256 * 128 * 3;
    float* wtf   = ws + o; o += 256 * 768;                  // fuse wt max

    run_block(x, 256, 128, P1, abuf, bxb, byb, off4, stats,
              wtc, wtdx, wtdy, wtf, nullptr, h1, stream);
    run_block(h1, 128, 256, P2, abuf, bxb, byb, off4, stats,
              wtc, wtdx, wtdy, wtf, x, (float*)d_out, stream);
}

// Round 2
// 1115.294 us; speedup vs baseline: 3.9826x; 3.9826x over previous
//
#include <hip/hip_runtime.h>
#include <cstddef>

#define B_   8
#define H_   80
#define W_   80
#define HW   6400

typedef __attribute__((ext_vector_type(8)))  short short8;
typedef __attribute__((ext_vector_type(16))) float f32x16;

__device__ __forceinline__ float bf2f(ushort u) {
    return __uint_as_float(((unsigned)u) << 16);
}
__device__ __forceinline__ ushort f2bf(float f) {
    unsigned u = __float_as_uint(f);
    u += 0x7FFF + ((u >> 16) & 1);   // RNE
    return (ushort)(u >> 16);
}
__device__ __forceinline__ f32x16 mfma16(short8 a, short8 b, f32x16 c) {
    return __builtin_amdgcn_mfma_f32_32x32x16_bf16(a, b, c, 0, 0, 0);
}

// ---------------------------------------------------------------------------
// x fp32 NCHW -> xh bf16 NHWC.  grid (HW/64, C/64, B), 256 thr, LDS transpose
// ---------------------------------------------------------------------------
__global__ __launch_bounds__(256) void transpose_x_kernel(
    const float* __restrict__ x, ushort* __restrict__ xh, int C) {
    __shared__ float s[64][65];
    int hw0 = blockIdx.x * 64, c0 = blockIdx.y * 64, b = blockIdx.z;
    int t = threadIdx.x;
    int hl = t & 63, cq = t >> 6;
    #pragma unroll
    for (int i = 0; i < 16; i++) {
        int cl = cq * 16 + i;
        s[cl][hl] = x[((size_t)(b * C + c0 + cl)) * HW + hw0 + hl];
    }
    __syncthreads();
    int cl = t & 63, hq = t >> 6;
    #pragma unroll
    for (int i = 0; i < 16; i++) {
        int hl2 = hq * 16 + i;
        xh[((size_t)(b * HW + hw0 + hl2)) * C + c0 + cl] = f2bf(s[cl][hl2]);
    }
}

// ---------------------------------------------------------------------------
// final: d_out[b][c][hw] = x[b][c][hw] + h2[b][hw][c]
// ---------------------------------------------------------------------------
__global__ __launch_bounds__(256) void final_add_kernel(
    const float* __restrict__ x, const ushort* __restrict__ h2,
    float* __restrict__ out, int C) {
    __shared__ float s[64][65];
    int hw0 = blockIdx.x * 64, c0 = blockIdx.y * 64, b = blockIdx.z;
    int t = threadIdx.x;
    int cl = t & 63, hq = t >> 6;
    #pragma unroll
    for (int i = 0; i < 16; i++) {
        int hl = hq * 16 + i;
        s[cl][hl] = bf2f(h2[((size_t)(b * HW + hw0 + hl)) * C + c0 + cl]);
    }
    __syncthreads();
    int hl = t & 63, cq = t >> 6;
    #pragma unroll
    for (int i = 0; i < 16; i++) {
        int cl2 = cq * 16 + i;
        size_t o = ((size_t)(b * C + c0 + cl2)) * HW + hw0 + hl;
        out[o] = x[o] + s[cl2][hl];
    }
}

// ---------------------------------------------------------------------------
// Weight prep: src fp32 [OC][CIN][T] -> dst bf16 [OC][T][CIN]
// ---------------------------------------------------------------------------
__global__ void wprep_kernel(const float* __restrict__ src,
                             ushort* __restrict__ dst, int OC, int CIN, int T) {
    int idx = blockIdx.x * 256 + threadIdx.x;
    if (idx >= OC * CIN * T) return;
    int oc = idx / (CIN * T);
    int r = idx - oc * CIN * T;
    int ci = r / T, t_ = r - ci * T;
    dst[((size_t)oc * T + t_) * CIN + ci] = f2bf(src[idx]);
}

// ---------------------------------------------------------------------------
// Offset conv (NHWC bf16 input): 4 maps = tanh(conv3x3) for ch {0,2,3,5}
// ---------------------------------------------------------------------------
__global__ __launch_bounds__(256) void off_conv_kernel(
    const ushort* __restrict__ xh,
    const float* __restrict__ wx_, const float* __restrict__ bx_,
    const float* __restrict__ wy_, const float* __restrict__ by_,
    float* __restrict__ off4, int CIN) {
    __shared__ float s_w[256 * 9];
    int m = blockIdx.y, b = blockIdx.z;
    int hw = blockIdx.x * 256 + threadIdx.x;
    int ch = (m == 0) ? 0 : (m == 1) ? 2 : (m == 2) ? 3 : 5;
    const float* wsrc = ((m < 2) ? wx_ : wy_) + (size_t)ch * CIN * 9;
    float bias = (m < 2) ? bx_[ch] : by_[ch];
    for (int i = threadIdx.x; i < CIN * 9; i += 256) s_w[i] = wsrc[i];
    __syncthreads();
    int h = hw / W_, w = hw - h * W_;
    float acc = bias;
    for (int ky = 0; ky < 3; ky++) {
        int yy = h + ky - 1;
        if (yy < 0 || yy >= H_) continue;
        for (int kx = 0; kx < 3; kx++) {
            int xx = w + kx - 1;
            if (xx < 0 || xx >= W_) continue;
            int tap = ky * 3 + kx;
            const ushort* row = xh + ((size_t)(b * HW + yy * W_ + xx)) * CIN;
            for (int cg = 0; cg < (CIN >> 3); cg++) {
                uint4 u = *(const uint4*)(row + cg * 8);
                const ushort* sv = (const ushort*)&u;
                #pragma unroll
                for (int j = 0; j < 8; j++)
                    acc += bf2f(sv[j]) * s_w[(cg * 8 + j) * 9 + tap];
            }
        }
    }
    off4[((size_t)b * 4 + m) * HW + hw] = tanhf(acc);
}

// ---------------------------------------------------------------------------
// Implicit conv3x3 + bias + SiLU via MFMA.  16x16 spatial tile, BN=64 oc,
// ci chunks of 32.  xh bf16 NHWC, wB bf16 [OC][9][CIN], out bf16 NHWC.
// grid (25, OC/64, B)
// ---------------------------------------------------------------------------
__global__ __launch_bounds__(256, 2) void conv3x3_mfma_kernel(
    const ushort* __restrict__ xh, const ushort* __restrict__ wB,
    const float* __restrict__ bias, ushort* __restrict__ out,
    int CIN, int OC) {
    __shared__ ushort s_x[18 * 18 * 40];   // [pix 18x18][ci 32 pad->40]
    __shared__ ushort s_w[576 * 32];       // [tap*64+oc][ci 32, XOR-swizzled]
    int tid = threadIdx.x;
    int ty0 = (blockIdx.x / 5) * 16, tx0 = (blockIdx.x % 5) * 16;
    int n0 = blockIdx.y * 64, b = blockIdx.z;
    int lane = tid & 63, wid = tid >> 6;
    int l31 = lane & 31, kg = lane >> 5;
    int wm = wid >> 1, wn = wid & 1;
    int pym[4], pxm[4];
    #pragma unroll
    for (int mf = 0; mf < 4; mf++) {
        int p = wm * 128 + mf * 32 + l31;
        pym[mf] = p >> 4; pxm[mf] = p & 15;
    }
    f32x16 acc[4] = {};
    for (int c0 = 0; c0 < CIN; c0 += 32) {
        __syncthreads();
        for (int u = tid; u < 1296; u += 256) {   // 324 pixels x 4 xui4
            int pid = u >> 2, ci8 = u & 3;
            int r = pid / 18, c = pid - r * 18;
            int gy = ty0 + r - 1, gx = tx0 + c - 1;
            uint4 v = make_uint4(0, 0, 0, 0);
            if ((unsigned)gy < H_ && (unsigned)gx < W_)
                v = *(const uint4*)(xh + ((size_t)(b * HW + gy * W_ + gx)) * CIN + c0 + ci8 * 8);
            *(uint4*)(s_x + pid * 40 + ci8 * 8) = v;
        }
        for (int u = tid; u < 2304; u += 256) {   // 9 taps x 64 oc x 4 ui4
            int R = u >> 2, ci8 = u & 3;
            int tap = R >> 6, oc = R & 63;
            uint4 v = *(const uint4*)(wB + ((size_t)(n0 + oc) * 9 + tap) * CIN + c0 + ci8 * 8);
            int phys = ci8 ^ (oc & 3);            // bank swizzle
            *(uint4*)(s_w + R * 32 + phys * 8) = v;
        }
        __syncthreads();
        #pragma unroll
        for (int tap = 0; tap < 9; tap++) {
            int dy = tap / 3, dx = tap - dy * 3;
            const ushort* swt = s_w + (tap * 64 + wn * 32 + l31) * 32;
            #pragma unroll
            for (int ks = 0; ks < 2; ks++) {
                int blk = (ks * 2 + kg) ^ (l31 & 3);
                short8 bfr = *(const short8*)(swt + blk * 8);
                #pragma unroll
                for (int mf = 0; mf < 4; mf++) {
                    int pix = (pym[mf] + dy) * 18 + (pxm[mf] + dx);
                    short8 afr = *(const short8*)(s_x + pix * 40 + ks * 16 + kg * 8);
                    acc[mf] = mfma16(afr, bfr, acc[mf]);
                }
            }
        }
    }
    int oc = n0 + wn * 32 + l31;
    float bb = bias[oc];
    #pragma unroll
    for (int mf = 0; mf < 4; mf++) {
        #pragma unroll
        for (int reg = 0; reg < 16; reg++) {
            int row = (reg & 3) + 8 * (reg >> 2) + 4 * kg;
            int p = wm * 128 + mf * 32 + row;
            int y = ty0 + (p >> 4), x = tx0 + (p & 15);
            float v = acc[mf][reg] + bb;
            v = v / (1.f + expf(-v));
            out[((size_t)(b * HW + y * W_ + x)) * OC + oc] = f2bf(v);
        }
    }
}

// ---------------------------------------------------------------------------
// Snake sampling -> As[mrel][k3][ci] bf16 for M-slice [m_base, m_base+25600)
// ---------------------------------------------------------------------------
__global__ void snake_sample_kernel(const ushort* __restrict__ xh,
                                    const float* __restrict__ off4,
                                    ushort* __restrict__ As,
                                    int CIN, int cshift, int morph, int m_base) {
    int idx = blockIdx.x * 256 + threadIdx.x;
    int total = 25600 * 3 * (CIN >> 3);
    if (idx >= total) return;
    int cig = idx & ((1 << cshift) - 1);
    int tmp = idx >> cshift;
    int mrel = tmp / 3;
    int k3 = tmp - mrel * 3;
    int m = m_base + mrel;
    int b = m / HW, hw = m - b * HW;
    int h = hw / W_, w = hw - h * W_;
    float bend = 0.f;
    if (k3 != 1) {
        int mp = (morph ? 2 : 0) + (k3 >> 1);
        bend = off4[((size_t)b * 4 + mp) * HW + hw];
    }
    int i0, i1; float wl;
    if (morph == 0) {
        float ys = fminf(fmaxf((float)h + bend, 0.f), 79.f);
        float y0f = floorf(ys);
        wl = ys - y0f;
        int y0 = (int)y0f, y1 = min(y0 + 1, 79);
        int xk = min(max(w + k3 - 1, 0), 79);
        i0 = y0 * W_ + xk; i1 = y1 * W_ + xk;
    } else {
        float xs = fminf(fmaxf((float)w + bend, 0.f), 79.f);
        float x0f = floorf(xs);
        wl = xs - x0f;
        int x0 = (int)x0f, x1 = min(x0 + 1, 79);
        int yk = min(max(h + k3 - 1, 0), 79);
        i0 = yk * W_ + x0; i1 = yk * W_ + x1;
    }
    uint4 u0 = *(const uint4*)(xh + ((size_t)b * HW + i0) * CIN + cig * 8);
    uint4 u1 = *(const uint4*)(xh + ((size_t)b * HW + i1) * CIN + cig * 8);
    const ushort* p0 = (const ushort*)&u0;
    const ushort* p1 = (const ushort*)&u1;
    ushort outv[8];
    #pragma unroll
    for (int j = 0; j < 8; j++)
        outv[j] = f2bf(bf2f(p0[j]) * (1.f - wl) + bf2f(p1[j]) * wl);
    *(uint4*)(As + ((size_t)mrel * 3 + k3) * CIN + cig * 8) = *(uint4*)outv;
}

// ---------------------------------------------------------------------------
// Generic 128x128 MFMA GEMM: C[m][n] = A[m][k] * B[n][k]^T + bias
// A split into up to 3 channel-parts (for fuse cat); parts 1,2 may apply
// GN scale/shift + relu during staging.  out bf16; epi_silu optional.
// grid (Mtiles, N/128)
// ---------------------------------------------------------------------------
__global__ __launch_bounds__(256, 2) void gemm128_kernel(
    const ushort* __restrict__ a0, const ushort* __restrict__ a1,
    const ushort* __restrict__ a2, int part_k,
    const ushort* __restrict__ Bw, int K, int N,
    const float* __restrict__ bias,
    const float* __restrict__ sc1, const float* __restrict__ sh1,
    const float* __restrict__ sc2, const float* __restrict__ sh2,
    ushort* __restrict__ out, int out_row0, int epi_silu) {
    __shared__ ushort s_a[128 * 72];
    __shared__ ushort s_b[128 * 72];
    int tid = threadIdx.x;
    int m0 = blockIdx.x * 128, n0 = blockIdx.y * 128;
    int lane = tid & 63, wid = tid >> 6;
    int l31 = lane & 31, kg = lane >> 5;
    int wm = wid >> 1, wn = wid & 1;
    f32x16 acc[2][2] = {};
    int nk = K >> 6;
    for (int kc = 0; kc < nk; kc++) {
        int kg64 = kc << 6;
        int part = kg64 / part_k;
        int koff = kg64 - part * part_k;
        const ushort* ap = (part == 0) ? a0 : (part == 1 ? a1 : a2);
        const float* sc = (part == 1) ? sc1 : sc2;
        const float* sh = (part == 1) ? sh1 : sh2;
        bool tf = (part > 0) && (sc1 != nullptr);
        __syncthreads();
        #pragma unroll
        for (int i = 0; i < 4; i++) {
            int u = tid + (i << 8);
            int r = u >> 3, cb = u & 7;
            uint4 v = *(const uint4*)(ap + (size_t)(m0 + r) * part_k + koff + cb * 8);
            if (tf) {
                int brow = (out_row0 + m0 + r) / HW;
                const float* scb = sc + (size_t)brow * part_k + koff + cb * 8;
                const float* shb = sh + (size_t)brow * part_k + koff + cb * 8;
                ushort* sv = (ushort*)&v;
                ushort tv[8];
                #pragma unroll
                for (int j = 0; j < 8; j++) {
                    float f = bf2f(sv[j]) * scb[j] + shb[j];
                    tv[j] = f2bf(fmaxf(f, 0.f));
                }
                v = *(uint4*)tv;
            }
            *(uint4*)(s_a + r * 72 + cb * 8) = v;
            uint4 wv = *(const uint4*)(Bw + (size_t)(n0 + r) * K + kg64 + cb * 8);
            *(uint4*)(s_b + r * 72 + cb * 8) = wv;
        }
        __syncthreads();
        #pragma unroll
        for (int ks = 0; ks < 4; ks++) {
            int co = ks * 16 + kg * 8;
            short8 af0 = *(const short8*)(s_a + (wm * 64 + l31) * 72 + co);
            short8 af1 = *(const short8*)(s_a + (wm * 64 + 32 + l31) * 72 + co);
            short8 bf0 = *(const short8*)(s_b + (wn * 64 + l31) * 72 + co);
            short8 bf1 = *(const short8*)(s_b + (wn * 64 + 32 + l31) * 72 + co);
            acc[0][0] = mfma16(af0, bf0, acc[0][0]);
            acc[0][1] = mfma16(af0, bf1, acc[0][1]);
            acc[1][0] = mfma16(af1, bf0, acc[1][0]);
            acc[1][1] = mfma16(af1, bf1, acc[1][1]);
        }
    }
    #pragma unroll
    for (int nf = 0; nf < 2; nf++) {
        int n = n0 + wn * 64 + nf * 32 + l31;
        float bb = bias[n];
        #pragma unroll
        for (int mf = 0; mf < 2; mf++) {
            #pragma unroll
            for (int reg = 0; reg < 16; reg++) {
                int row = (reg & 3) + 8 * (reg >> 2) + 4 * kg;
                int m = m0 + wm * 64 + mf * 32 + row;
                float v = acc[mf][nf][reg] + bb;
                if (epi_silu) v = v / (1.f + expf(-v));
                out[(size_t)(out_row0 + m) * N + n] = f2bf(v);
            }
        }
    }
}

// ---------------------------------------------------------------------------
// GN stats from bf16 NHWC: one block per (b, group-of-4)
// ---------------------------------------------------------------------------
__global__ __launch_bounds__(256) void gn_stats_kernel(
    const ushort* __restrict__ src, float* __restrict__ mr, int C) {
    int G = C >> 2;
    int bg = blockIdx.x;
    int b = bg / G, g = bg - b * G;
    float s = 0.f, sq = 0.f;
    for (int hw = threadIdx.x; hw < HW; hw += 256) {
        const ushort* p = src + ((size_t)(b * HW + hw)) * C + g * 4;
        ushort4 u = *(const ushort4*)p;
        float v0 = bf2f(u.x), v1 = bf2f(u.y), v2 = bf2f(u.z), v3 = bf2f(u.w);
        s += v0 + v1 + v2 + v3;
        sq += v0 * v0 + v1 * v1 + v2 * v2 + v3 * v3;
    }
    #pragma unroll
    for (int off = 32; off; off >>= 1) {
        s += __shfl_down(s, off);
        sq += __shfl_down(sq, off);
    }
    __shared__ float sh[2][4];
    int wid = threadIdx.x >> 6, lane = threadIdx.x & 63;
    if (lane == 0) { sh[0][wid] = s; sh[1][wid] = sq; }
    __syncthreads();
    if (threadIdx.x == 0) {
        s = sh[0][0] + sh[0][1] + sh[0][2] + sh[0][3];
        sq = sh[1][0] + sh[1][1] + sh[1][2] + sh[1][3];
        float mean = s / (4.f * HW);
        float var = sq / (4.f * HW) - mean * mean;
        mr[bg * 2] = mean;
        mr[bg * 2 + 1] = rsqrtf(var + 1e-5f);
    }
}

// ---------------------------------------------------------------------------
// GN finalize: scale[b][c] = rstd*gamma, shift[b][c] = beta - mean*rstd*gamma
// ---------------------------------------------------------------------------
__global__ void gn_finalize_kernel(const float* __restrict__ mr,
                                   const float* __restrict__ gamma,
                                   const float* __restrict__ beta,
                                   float* __restrict__ sc, float* __restrict__ sh,
                                   int C) {
    int idx = blockIdx.x * 256 + threadIdx.x;
    if (idx >= B_ * C) return;
    int b = idx / C, c = idx - b * C;
    int g = c >> 2, G = C >> 2;
    float mean = mr[(b * G + g) * 2];
    float rs = mr[(b * G + g) * 2 + 1];
    float s = rs * gamma[c];
    sc[idx] = s;
    sh[idx] = beta[c] - mean * s;
}

// ---------------------------------------------------------------------------
// Host orchestration
// ---------------------------------------------------------------------------
struct BlkBuf {
    ushort *xh, *abuf, *bqx, *bqy, *As, *hout;
    float *off4, *mrx, *mry, *scx, *shx, *scy, *shy;
    ushort *wc, *wdx, *wdy, *wf;
};

static void run_block(const BlkBuf& B, int CIN, int OC,
                      const float* const* P, hipStream_t stream) {
    dim3 blk(256);
    int cshift = (CIN == 256) ? 5 : 4;  // log2(CIN/8)
    off_conv_kernel<<<dim3(25, 4, B_), blk, 0, stream>>>(
        B.xh, P[2], P[3], P[8], P[9], B.off4, CIN);
    conv3x3_mfma_kernel<<<dim3(25, OC / 64, B_), blk, 0, stream>>>(
        B.xh, B.wc, P[1], B.abuf, CIN, OC);
    int K3 = 3 * CIN;
    int samp_grid = (25600 * 3 * (CIN >> 3)) / 256;
    for (int morph = 0; morph < 2; morph++) {
        ushort* bq = morph ? B.bqy : B.bqx;
        const ushort* wd = morph ? B.wdy : B.wdx;
        const float* dbias = morph ? P[11] : P[5];
        for (int s = 0; s < 2; s++) {
            int m_base = s * 25600;
            snake_sample_kernel<<<samp_grid, blk, 0, stream>>>(
                B.xh, B.off4, B.As, CIN, cshift, morph, m_base);
            gemm128_kernel<<<dim3(200, OC / 128), blk, 0, stream>>>(
                B.As, B.As, B.As, K3, wd, K3, OC, dbias,
                nullptr, nullptr, nullptr, nullptr, bq, m_base, 0);
        }
    }
    int G = OC / 4;
    gn_stats_kernel<<<B_ * G, blk, 0, stream>>>(B.bqx, B.mrx, OC);
    gn_stats_kernel<<<B_ * G, blk, 0, stream>>>(B.bqy, B.mry, OC);
    int fgrid = (B_ * OC + 255) / 256;
    gn_finalize_kernel<<<fgrid, blk, 0, stream>>>(B.mrx, P[6], P[7], B.scx, B.shx, OC);
    gn_finalize_kernel<<<fgrid, blk, 0, stream>>>(B.mry, P[12], P[13], B.scy, B.shy, OC);
    gemm128_kernel<<<dim3(400, OC / 128), blk, 0, stream>>>(
        B.abuf, B.bqx, B.bqy, OC, B.wf, 3 * OC, OC, P[15],
        B.scx, B.shx, B.scy, B.shy, B.hout, 0, 1);
}

extern "C" void kernel_launch(void* const* d_in, const int* in_sizes, int n_in,
                              void* d_out, int out_size, void* d_ws, size_t ws_size,
                              hipStream_t stream) {
    const float* x = (const float*)d_in[0];
    const float* P1[16];
    const float* P2[16];
    for (int i = 0; i < 16; i++) {
        P1[i] = (const float*)d_in[1 + i];
        P2[i] = (const float*)d_in[17 + i];
    }
    char* base = (char*)d_ws;
    size_t off = 0;
    auto alloc = [&](size_t bytes) -> char* {
        off = (off + 255) & ~(size_t)255;
        char* p = base + off;
        off += bytes;
        return p;
    };
    ushort* xh   = (ushort*)alloc((size_t)B_ * HW * 256 * 2);  // block2: h2 out
    ushort* abuf = (ushort*)alloc((size_t)B_ * HW * 256 * 2);
    ushort* bqx  = (ushort*)alloc((size_t)B_ * HW * 256 * 2);
    ushort* bqy  = (ushort*)alloc((size_t)B_ * HW * 256 * 2);
    ushort* As   = (ushort*)alloc((size_t)25600 * 768 * 2);
    ushort* h1   = (ushort*)alloc((size_t)B_ * HW * 128 * 2);
    float*  off4 = (float*)alloc((size_t)B_ * 4 * HW * 4);
    float*  mrx  = (float*)alloc(4096);
    float*  mry  = (float*)alloc(4096);
    float*  scx  = (float*)alloc(B_ * 256 * 4);
    float*  shx  = (float*)alloc(B_ * 256 * 4);
    float*  scy  = (float*)alloc(B_ * 256 * 4);
    float*  shy  = (float*)alloc(B_ * 256 * 4);
    ushort* wc1  = (ushort*)alloc((size_t)128 * 9 * 256 * 2);
    ushort* wc2  = (ushort*)alloc((size_t)256 * 9 * 128 * 2);
    ushort* wdx1 = (ushort*)alloc((size_t)128 * 3 * 256 * 2);
    ushort* wdy1 = (ushort*)alloc((size_t)128 * 3 * 256 * 2);
    ushort* wdx2 = (ushort*)alloc((size_t)256 * 3 * 128 * 2);
    ushort* wdy2 = (ushort*)alloc((size_t)256 * 3 * 128 * 2);
    ushort* wf1  = (ushort*)alloc((size_t)128 * 384 * 2);
    ushort* wf2  = (ushort*)alloc((size_t)256 * 768 * 2);

    dim3 blk(256);
    auto wp = [&](const float* s, ushort* d, int OC, int CIN, int T) {
        int n = OC * CIN * T;
        wprep_kernel<<<(n + 255) / 256, blk, 0, stream>>>(s, d, OC, CIN, T);
    };
    wp(P1[0], wc1, 128, 256, 9);
    wp(P1[4], wdx1, 128, 256, 3);
    wp(P1[10], wdy1, 128, 256, 3);
    wp(P1[14], wf1, 128, 384, 1);
    wp(P2[0], wc2, 256, 128, 9);
    wp(P2[4], wdx2, 256, 128, 3);
    wp(P2[10], wdy2, 256, 128, 3);
    wp(P2[14], wf2, 256, 768, 1);

    transpose_x_kernel<<<dim3(100, 4, B_), blk, 0, stream>>>(x, xh, 256);

    BlkBuf B1 = {xh, abuf, bqx, bqy, As, h1, off4, mrx, mry, scx, shx, scy, shy,
                 wc1, wdx1, wdy1, wf1};
    run_block(B1, 256, 128, P1, stream);

    ushort* h2 = xh;  // reuse slab (xh dead after block1)
    BlkBuf B2 = {h1, abuf, bqx, bqy, As, h2, off4, mrx, mry, scx, shx, scy, shy,
                 wc2, wdx2, wdy2, wf2};
    run_block(B2, 128, 256, P2, stream);

    final_add_kernel<<<dim3(100, 4, B_), blk, 0, stream>>>(x, h2, (float*)d_out, 256);
}

// Round 4
// 702.995 us; speedup vs baseline: 6.3183x; 1.5865x over previous
//
#include <hip/hip_runtime.h>
#include <cstddef>

#define B_   8
#define H_   80
#define W_   80
#define HW   6400

typedef __attribute__((ext_vector_type(8)))  short short8;
typedef __attribute__((ext_vector_type(16))) float f32x16;

__device__ __forceinline__ float bf2f(ushort u) {
    return __uint_as_float(((unsigned)u) << 16);
}
__device__ __forceinline__ ushort f2bf(float f) {
    unsigned u = __float_as_uint(f);
    u += 0x7FFF + ((u >> 16) & 1);   // RNE
    return (ushort)(u >> 16);
}
__device__ __forceinline__ f32x16 mfma16(short8 a, short8 b, f32x16 c) {
    return __builtin_amdgcn_mfma_f32_32x32x16_bf16(a, b, c, 0, 0, 0);
}

// ---------------------------------------------------------------------------
// x fp32 NCHW -> xh bf16 NHWC.  grid (HW/64, C/64, B)
// ---------------------------------------------------------------------------
__global__ __launch_bounds__(256) void transpose_x_kernel(
    const float* __restrict__ x, ushort* __restrict__ xh, int C) {
    __shared__ float s[64][65];
    int hw0 = blockIdx.x * 64, c0 = blockIdx.y * 64, b = blockIdx.z;
    int t = threadIdx.x;
    int hl = t & 63, cq = t >> 6;
    #pragma unroll
    for (int i = 0; i < 16; i++) {
        int cl = cq * 16 + i;
        s[cl][hl] = x[((size_t)(b * C + c0 + cl)) * HW + hw0 + hl];
    }
    __syncthreads();
    int cl = t & 63, hq = t >> 6;
    #pragma unroll
    for (int i = 0; i < 16; i++) {
        int hl2 = hq * 16 + i;
        xh[((size_t)(b * HW + hw0 + hl2)) * C + c0 + cl] = f2bf(s[cl][hl2]);
    }
}

// ---------------------------------------------------------------------------
// final: d_out[b][c][hw] = x[b][c][hw] + h2[b][hw][c]
// ---------------------------------------------------------------------------
__global__ __launch_bounds__(256) void final_add_kernel(
    const float* __restrict__ x, const ushort* __restrict__ h2,
    float* __restrict__ out, int C) {
    __shared__ float s[64][65];
    int hw0 = blockIdx.x * 64, c0 = blockIdx.y * 64, b = blockIdx.z;
    int t = threadIdx.x;
    int cl = t & 63, hq = t >> 6;
    #pragma unroll
    for (int i = 0; i < 16; i++) {
        int hl = hq * 16 + i;
        s[cl][hl] = bf2f(h2[((size_t)(b * HW + hw0 + hl)) * C + c0 + cl]);
    }
    __syncthreads();
    int hl = t & 63, cq = t >> 6;
    #pragma unroll
    for (int i = 0; i < 16; i++) {
        int cl2 = cq * 16 + i;
        size_t o = ((size_t)(b * C + c0 + cl2)) * HW + hw0 + hl;
        out[o] = x[o] + s[cl2][hl];
    }
}

// ---------------------------------------------------------------------------
// Weight prep: src fp32 [OC][CIN][T] -> dst bf16 [OC][T][CIN]
// ---------------------------------------------------------------------------
__global__ void wprep_kernel(const float* __restrict__ src,
                             ushort* __restrict__ dst, int OC, int CIN, int T) {
    int idx = blockIdx.x * 256 + threadIdx.x;
    if (idx >= OC * CIN * T) return;
    int oc = idx / (CIN * T);
    int r = idx - oc * CIN * T;
    int ci = r / T, t_ = r - ci * T;
    dst[((size_t)oc * T + t_) * CIN + ci] = f2bf(src[idx]);
}

// ---------------------------------------------------------------------------
// Offset weight prep: pack 4 wanted channels (+28 zero pads) of the two
// offset convs into dst bf16 [32][9][CIN]; bias (4 entries) into bdst.
// oc map: 0 -> offx ch0, 1 -> offx ch2, 2 -> offy ch3, 3 -> offy ch5
// ---------------------------------------------------------------------------
__global__ void wprep_off_kernel(const float* __restrict__ wx_,
                                 const float* __restrict__ bx_,
                                 const float* __restrict__ wy_,
                                 const float* __restrict__ by_,
                                 ushort* __restrict__ dst,
                                 float* __restrict__ bdst, int CIN) {
    int idx = blockIdx.x * 256 + threadIdx.x;
    if (idx < 4) {
        const int chs[4] = {0, 2, 3, 5};
        bdst[idx] = (idx < 2) ? bx_[chs[idx]] : by_[chs[idx]];
    }
    if (idx >= 32 * 9 * CIN) return;
    int oc = idx / (9 * CIN);
    int r = idx - oc * 9 * CIN;
    int tap = r / CIN, ci = r - tap * CIN;
    float v = 0.f;
    if (oc < 4) {
        const int chs[4] = {0, 2, 3, 5};
        const float* src = (oc < 2) ? wx_ : wy_;
        v = src[((size_t)chs[oc] * CIN + ci) * 9 + tap];
    }
    dst[idx] = f2bf(v);
}

// ---------------------------------------------------------------------------
// Offset conv via MFMA: 16x16 spatial tile, N=32 (4 real oc), tanh epilogue.
// grid (25, B)
// ---------------------------------------------------------------------------
__global__ __launch_bounds__(256, 2) void off_conv_mfma_kernel(
    const ushort* __restrict__ xh, const ushort* __restrict__ wB,
    const float* __restrict__ bias, float* __restrict__ off4, int CIN) {
    __shared__ ushort s_x[18 * 18 * 40];
    __shared__ ushort s_w[288 * 32];
    int tid = threadIdx.x;
    int ty0 = (blockIdx.x / 5) * 16, tx0 = (blockIdx.x % 5) * 16;
    int b = blockIdx.y;
    int lane = tid & 63, wid = tid >> 6;
    int l31 = lane & 31, kg = lane >> 5;
    int pym[2], pxm[2];
    #pragma unroll
    for (int mf = 0; mf < 2; mf++) {
        int p = wid * 64 + mf * 32 + l31;
        pym[mf] = p >> 4; pxm[mf] = p & 15;
    }
    f32x16 acc[2] = {};
    for (int c0 = 0; c0 < CIN; c0 += 32) {
        __syncthreads();
        for (int u = tid; u < 1296; u += 256) {
            int pid = u >> 2, ci8 = u & 3;
            int r = pid / 18, c = pid - r * 18;
            int gy = ty0 + r - 1, gx = tx0 + c - 1;
            uint4 v = make_uint4(0, 0, 0, 0);
            if ((unsigned)gy < H_ && (unsigned)gx < W_)
                v = *(const uint4*)(xh + ((size_t)(b * HW + gy * W_ + gx)) * CIN + c0 + ci8 * 8);
            *(uint4*)(s_x + pid * 40 + ci8 * 8) = v;
        }
        for (int u = tid; u < 1152; u += 256) {   // 9 taps x 32 oc x 4 ui4
            int R = u >> 2, ci8 = u & 3;
            int tap = R >> 5, oc = R & 31;
            uint4 v = *(const uint4*)(wB + ((size_t)oc * 9 + tap) * CIN + c0 + ci8 * 8);
            int phys = ci8 ^ (oc & 3);
            *(uint4*)(s_w + R * 32 + phys * 8) = v;
        }
        __syncthreads();
        #pragma unroll
        for (int tap = 0; tap < 9; tap++) {
            int dy = tap / 3, dx = tap - dy * 3;
            const ushort* swt = s_w + (tap * 32 + l31) * 32;
            #pragma unroll
            for (int ks = 0; ks < 2; ks++) {
                int blk = (ks * 2 + kg) ^ (l31 & 3);
                short8 bfr = *(const short8*)(swt + blk * 8);
                #pragma unroll
                for (int mf = 0; mf < 2; mf++) {
                    int pix = (pym[mf] + dy) * 18 + (pxm[mf] + dx);
                    short8 afr = *(const short8*)(s_x + pix * 40 + ks * 16 + kg * 8);
                    acc[mf] = mfma16(afr, bfr, acc[mf]);
                }
            }
        }
    }
    int oc = l31;
    if (oc < 4) {
        float bb = bias[oc];
        #pragma unroll
        for (int mf = 0; mf < 2; mf++) {
            #pragma unroll
            for (int reg = 0; reg < 16; reg++) {
                int row = (reg & 3) + 8 * (reg >> 2) + 4 * kg;
                int p = wid * 64 + mf * 32 + row;
                int y = ty0 + (p >> 4), x = tx0 + (p & 15);
                off4[((size_t)b * 4 + oc) * HW + y * W_ + x] = tanhf(acc[mf][reg] + bb);
            }
        }
    }
}

// ---------------------------------------------------------------------------
// Implicit conv3x3 + bias + SiLU via MFMA.  16x16 spatial tile, BN=64 oc.
// grid (25, OC/64, B)
// ---------------------------------------------------------------------------
__global__ __launch_bounds__(256, 2) void conv3x3_mfma_kernel(
    const ushort* __restrict__ xh, const ushort* __restrict__ wB,
    const float* __restrict__ bias, ushort* __restrict__ out,
    int CIN, int OC) {
    __shared__ ushort s_x[18 * 18 * 40];
    __shared__ ushort s_w[576 * 32];
    int tid = threadIdx.x;
    int ty0 = (blockIdx.x / 5) * 16, tx0 = (blockIdx.x % 5) * 16;
    int n0 = blockIdx.y * 64, b = blockIdx.z;
    int lane = tid & 63, wid = tid >> 6;
    int l31 = lane & 31, kg = lane >> 5;
    int wm = wid >> 1, wn = wid & 1;
    int pym[4], pxm[4];
    #pragma unroll
    for (int mf = 0; mf < 4; mf++) {
        int p = wm * 128 + mf * 32 + l31;
        pym[mf] = p >> 4; pxm[mf] = p & 15;
    }
    f32x16 acc[4] = {};
    for (int c0 = 0; c0 < CIN; c0 += 32) {
        __syncthreads();
        for (int u = tid; u < 1296; u += 256) {
            int pid = u >> 2, ci8 = u & 3;
            int r = pid / 18, c = pid - r * 18;
            int gy = ty0 + r - 1, gx = tx0 + c - 1;
            uint4 v = make_uint4(0, 0, 0, 0);
            if ((unsigned)gy < H_ && (unsigned)gx < W_)
                v = *(const uint4*)(xh + ((size_t)(b * HW + gy * W_ + gx)) * CIN + c0 + ci8 * 8);
            *(uint4*)(s_x + pid * 40 + ci8 * 8) = v;
        }
        for (int u = tid; u < 2304; u += 256) {
            int R = u >> 2, ci8 = u & 3;
            int tap = R >> 6, oc = R & 63;
            uint4 v = *(const uint4*)(wB + ((size_t)(n0 + oc) * 9 + tap) * CIN + c0 + ci8 * 8);
            int phys = ci8 ^ (oc & 3);
            *(uint4*)(s_w + R * 32 + phys * 8) = v;
        }
        __syncthreads();
        #pragma unroll
        for (int tap = 0; tap < 9; tap++) {
            int dy = tap / 3, dx = tap - dy * 3;
            const ushort* swt = s_w + (tap * 64 + wn * 32 + l31) * 32;
            #pragma unroll
            for (int ks = 0; ks < 2; ks++) {
                int blk = (ks * 2 + kg) ^ (l31 & 3);
                short8 bfr = *(const short8*)(swt + blk * 8);
                #pragma unroll
                for (int mf = 0; mf < 4; mf++) {
                    int pix = (pym[mf] + dy) * 18 + (pxm[mf] + dx);
                    short8 afr = *(const short8*)(s_x + pix * 40 + ks * 16 + kg * 8);
                    acc[mf] = mfma16(afr, bfr, acc[mf]);
                }
            }
        }
    }
    int oc = n0 + wn * 32 + l31;
    float bb = bias[oc];
    #pragma unroll
    for (int mf = 0; mf < 4; mf++) {
        #pragma unroll
        for (int reg = 0; reg < 16; reg++) {
            int row = (reg & 3) + 8 * (reg >> 2) + 4 * kg;
            int p = wm * 128 + mf * 32 + row;
            int y = ty0 + (p >> 4), x = tx0 + (p & 15);
            float v = acc[mf][reg] + bb;
            v = v / (1.f + expf(-v));
            out[((size_t)(b * HW + y * W_ + x)) * OC + oc] = f2bf(v);
        }
    }
}

// ---------------------------------------------------------------------------
// Snake-conv GEMM with fused bilinear gather.  A[m][k3*CIN+ci] gathered
// from xh via off4; B = wd [OC][3][CIN].  out bf16 [m][oc] (NHWC).
// grid (400, OC/128)
// ---------------------------------------------------------------------------
__global__ __launch_bounds__(256, 2) void dsc_gemm_kernel(
    const ushort* __restrict__ xh, const float* __restrict__ off4,
    const ushort* __restrict__ Bw, const float* __restrict__ bias,
    ushort* __restrict__ out, int CIN, int OC, int morph) {
    __shared__ ushort s_a[128 * 72];
    __shared__ ushort s_b[128 * 72];
    __shared__ int   s_i0[3][128];
    __shared__ int   s_i1[3][128];
    __shared__ float s_wl[3][128];
    int tid = threadIdx.x;
    int m0 = blockIdx.x * 128, n0 = blockIdx.y * 128;
    int b = m0 / HW, hw0 = m0 - b * HW;    // 6400 % 128 == 0: tile within b
    for (int u = tid; u < 384; u += 256) { // FIX R3: 384 entries, 256 threads
        int k3 = u >> 7, r = u & 127;
        int hw = hw0 + r;
        int h = hw / W_, w = hw - h * W_;
        float bend = 0.f;
        if (k3 != 1) {
            int mp = (morph ? 2 : 0) + (k3 >> 1);
            bend = off4[((size_t)b * 4 + mp) * HW + hw];
        }
        int i0, i1; float wl;
        if (morph == 0) {
            float ys = fminf(fmaxf((float)h + bend, 0.f), 79.f);
            float y0f = floorf(ys); wl = ys - y0f;
            int y0 = (int)y0f, y1 = min(y0 + 1, 79);
            int xk = min(max(w + k3 - 1, 0), 79);
            i0 = y0 * W_ + xk; i1 = y1 * W_ + xk;
        } else {
            float xs = fminf(fmaxf((float)w + bend, 0.f), 79.f);
            float x0f = floorf(xs); wl = xs - x0f;
            int x0 = (int)x0f, x1 = min(x0 + 1, 79);
            int yk = min(max(h + k3 - 1, 0), 79);
            i0 = yk * W_ + x0; i1 = yk * W_ + x1;
        }
        s_i0[k3][r] = i0; s_i1[k3][r] = i1; s_wl[k3][r] = wl;
    }
    int lane = tid & 63, wid = tid >> 6;
    int l31 = lane & 31, kg = lane >> 5;
    int wm = wid >> 1, wn = wid & 1;
    f32x16 acc[2][2] = {};
    int K = 3 * CIN, nk = K >> 6;
    const ushort* xb = xh + (size_t)b * HW * CIN;
    for (int kc = 0; kc < nk; kc++) {
        int kg64 = kc << 6;
        int k3 = kg64 / CIN;              // uniform per kc (64 | CIN)
        int cioff = kg64 - k3 * CIN;
        __syncthreads();
        #pragma unroll
        for (int i = 0; i < 4; i++) {
            int u = tid + (i << 8);
            int r = u >> 3, cb = u & 7;
            int ci = cioff + cb * 8;
            float wl = s_wl[k3][r];
            uint4 u0 = *(const uint4*)(xb + (size_t)s_i0[k3][r] * CIN + ci);
            uint4 u1 = *(const uint4*)(xb + (size_t)s_i1[k3][r] * CIN + ci);
            const ushort* p0 = (const ushort*)&u0;
            const ushort* p1 = (const ushort*)&u1;
            ushort tv[8];
            #pragma unroll
            for (int j = 0; j < 8; j++) {
                float f0 = bf2f(p0[j]);
                tv[j] = f2bf(f0 + (bf2f(p1[j]) - f0) * wl);
            }
            *(uint4*)(s_a + r * 72 + cb * 8) = *(uint4*)tv;
            uint4 wv = *(const uint4*)(Bw + (size_t)(n0 + r) * K + kg64 + cb * 8);
            *(uint4*)(s_b + r * 72 + cb * 8) = wv;
        }
        __syncthreads();
        #pragma unroll
        for (int ks = 0; ks < 4; ks++) {
            int co = ks * 16 + kg * 8;
            short8 af0 = *(const short8*)(s_a + (wm * 64 + l31) * 72 + co);
            short8 af1 = *(const short8*)(s_a + (wm * 64 + 32 + l31) * 72 + co);
            short8 bf0 = *(const short8*)(s_b + (wn * 64 + l31) * 72 + co);
            short8 bf1 = *(const short8*)(s_b + (wn * 64 + 32 + l31) * 72 + co);
            acc[0][0] = mfma16(af0, bf0, acc[0][0]);
            acc[0][1] = mfma16(af0, bf1, acc[0][1]);
            acc[1][0] = mfma16(af1, bf0, acc[1][0]);
            acc[1][1] = mfma16(af1, bf1, acc[1][1]);
        }
    }
    #pragma unroll
    for (int nf = 0; nf < 2; nf++) {
        int n = n0 + wn * 64 + nf * 32 + l31;
        float bb = bias[n];
        #pragma unroll
        for (int mf = 0; mf < 2; mf++) {
            #pragma unroll
            for (int reg = 0; reg < 16; reg++) {
                int row = (reg & 3) + 8 * (reg >> 2) + 4 * kg;
                int m = m0 + wm * 64 + mf * 32 + row;
                out[(size_t)m * OC + n] = f2bf(acc[mf][nf][reg] + bb);
            }
        }
    }
}

// ---------------------------------------------------------------------------
// Generic 128x128 MFMA GEMM over concat-A (up to 3 parts), GN transform on
// parts 1,2, SiLU epilogue.  grid (400, N/128)
// ---------------------------------------------------------------------------
__global__ __launch_bounds__(256, 2) void gemm128_kernel(
    const ushort* __restrict__ a0, const ushort* __restrict__ a1,
    const ushort* __restrict__ a2, int part_k,
    const ushort* __restrict__ Bw, int K, int N,
    const float* __restrict__ bias,
    const float* __restrict__ sc1, const float* __restrict__ sh1,
    const float* __restrict__ sc2, const float* __restrict__ sh2,
    ushort* __restrict__ out, int epi_silu) {
    __shared__ ushort s_a[128 * 72];
    __shared__ ushort s_b[128 * 72];
    int tid = threadIdx.x;
    int m0 = blockIdx.x * 128, n0 = blockIdx.y * 128;
    int lane = tid & 63, wid = tid >> 6;
    int l31 = lane & 31, kg = lane >> 5;
    int wm = wid >> 1, wn = wid & 1;
    f32x16 acc[2][2] = {};
    int nk = K >> 6;
    for (int kc = 0; kc < nk; kc++) {
        int kg64 = kc << 6;
        int part = kg64 / part_k;
        int koff = kg64 - part * part_k;
        const ushort* ap = (part == 0) ? a0 : (part == 1 ? a1 : a2);
        const float* sc = (part == 1) ? sc1 : sc2;
        const float* sh = (part == 1) ? sh1 : sh2;
        bool tf = (part > 0) && (sc1 != nullptr);
        __syncthreads();
        #pragma unroll
        for (int i = 0; i < 4; i++) {
            int u = tid + (i << 8);
            int r = u >> 3, cb = u & 7;
            uint4 v = *(const uint4*)(ap + (size_t)(m0 + r) * part_k + koff + cb * 8);
            if (tf) {
                int brow = (m0 + r) / HW;
                const float* scb = sc + (size_t)brow * part_k + koff + cb * 8;
                const float* shb = sh + (size_t)brow * part_k + koff + cb * 8;
                ushort* sv = (ushort*)&v;
                ushort tv[8];
                #pragma unroll
                for (int j = 0; j < 8; j++) {
                    float f = bf2f(sv[j]) * scb[j] + shb[j];
                    tv[j] = f2bf(fmaxf(f, 0.f));
                }
                v = *(uint4*)tv;
            }
            *(uint4*)(s_a + r * 72 + cb * 8) = v;
            uint4 wv = *(const uint4*)(Bw + (size_t)(n0 + r) * K + kg64 + cb * 8);
            *(uint4*)(s_b + r * 72 + cb * 8) = wv;
        }
        __syncthreads();
        #pragma unroll
        for (int ks = 0; ks < 4; ks++) {
            int co = ks * 16 + kg * 8;
            short8 af0 = *(const short8*)(s_a + (wm * 64 + l31) * 72 + co);
            short8 af1 = *(const short8*)(s_a + (wm * 64 + 32 + l31) * 72 + co);
            short8 bf0 = *(const short8*)(s_b + (wn * 64 + l31) * 72 + co);
            short8 bf1 = *(const short8*)(s_b + (wn * 64 + 32 + l31) * 72 + co);
            acc[0][0] = mfma16(af0, bf0, acc[0][0]);
            acc[0][1] = mfma16(af0, bf1, acc[0][1]);
            acc[1][0] = mfma16(af1, bf0, acc[1][0]);
            acc[1][1] = mfma16(af1, bf1, acc[1][1]);
        }
    }
    #pragma unroll
    for (int nf = 0; nf < 2; nf++) {
        int n = n0 + wn * 64 + nf * 32 + l31;
        float bb = bias[n];
        #pragma unroll
        for (int mf = 0; mf < 2; mf++) {
            #pragma unroll
            for (int reg = 0; reg < 16; reg++) {
                int row = (reg & 3) + 8 * (reg >> 2) + 4 * kg;
                int m = m0 + wm * 64 + mf * 32 + row;
                float v = acc[mf][nf][reg] + bb;
                if (epi_silu) v = v / (1.f + expf(-v));
                out[(size_t)m * N + n] = f2bf(v);
            }
        }
    }
}

// ---------------------------------------------------------------------------
// GN stats from bf16 NHWC: one block per (b, group-of-4)
// ---------------------------------------------------------------------------
__global__ __launch_bounds__(256) void gn_stats_kernel(
    const ushort* __restrict__ src, float* __restrict__ mr, int C) {
    int G = C >> 2;
    int bg = blockIdx.x;
    int b = bg / G, g = bg - b * G;
    float s = 0.f, sq = 0.f;
    for (int hw = threadIdx.x; hw < HW; hw += 256) {
        const ushort* p = src + ((size_t)(b * HW + hw)) * C + g * 4;
        ushort4 u = *(const ushort4*)p;
        float v0 = bf2f(u.x), v1 = bf2f(u.y), v2 = bf2f(u.z), v3 = bf2f(u.w);
        s += v0 + v1 + v2 + v3;
        sq += v0 * v0 + v1 * v1 + v2 * v2 + v3 * v3;
    }
    #pragma unroll
    for (int off = 32; off; off >>= 1) {
        s += __shfl_down(s, off);
        sq += __shfl_down(sq, off);
    }
    __shared__ float sh[2][4];
    int wid = threadIdx.x >> 6, lane = threadIdx.x & 63;
    if (lane == 0) { sh[0][wid] = s; sh[1][wid] = sq; }
    __syncthreads();
    if (threadIdx.x == 0) {
        s = sh[0][0] + sh[0][1] + sh[0][2] + sh[0][3];
        sq = sh[1][0] + sh[1][1] + sh[1][2] + sh[1][3];
        float mean = s / (4.f * HW);
        float var = sq / (4.f * HW) - mean * mean;
        mr[bg * 2] = mean;
        mr[bg * 2 + 1] = rsqrtf(var + 1e-5f);
    }
}

// ---------------------------------------------------------------------------
// GN finalize: scale[b][c] = rstd*gamma, shift[b][c] = beta - mean*rstd*gamma
// ---------------------------------------------------------------------------
__global__ void gn_finalize_kernel(const float* __restrict__ mr,
                                   const float* __restrict__ gamma,
                                   const float* __restrict__ beta,
                                   float* __restrict__ sc, float* __restrict__ sh,
                                   int C) {
    int idx = blockIdx.x * 256 + threadIdx.x;
    if (idx >= B_ * C) return;
    int b = idx / C, c = idx - b * C;
    int g = c >> 2, G = C >> 2;
    float mean = mr[(b * G + g) * 2];
    float rs = mr[(b * G + g) * 2 + 1];
    float s = rs * gamma[c];
    sc[idx] = s;
    sh[idx] = beta[c] - mean * s;
}

// ---------------------------------------------------------------------------
// Host orchestration
// ---------------------------------------------------------------------------
struct BlkBuf {
    ushort *xh, *abuf, *bqx, *bqy, *hout;
    float *off4, *mrx, *mry, *scx, *shx, *scy, *shy, *boff;
    ushort *wc, *wdx, *wdy, *wf, *woff;
};

static void run_block(const BlkBuf& B, int CIN, int OC,
                      const float* const* P, hipStream_t stream) {
    dim3 blk(256);
    off_conv_mfma_kernel<<<dim3(25, B_), blk, 0, stream>>>(
        B.xh, B.woff, B.boff, B.off4, CIN);
    conv3x3_mfma_kernel<<<dim3(25, OC / 64, B_), blk, 0, stream>>>(
        B.xh, B.wc, P[1], B.abuf, CIN, OC);
    dsc_gemm_kernel<<<dim3(400, OC / 128), blk, 0, stream>>>(
        B.xh, B.off4, B.wdx, P[5], B.bqx, CIN, OC, 0);
    dsc_gemm_kernel<<<dim3(400, OC / 128), blk, 0, stream>>>(
        B.xh, B.off4, B.wdy, P[11], B.bqy, CIN, OC, 1);
    int G = OC / 4;
    gn_stats_kernel<<<B_ * G, blk, 0, stream>>>(B.bqx, B.mrx, OC);
    gn_stats_kernel<<<B_ * G, blk, 0, stream>>>(B.bqy, B.mry, OC);
    int fgrid = (B_ * OC + 255) / 256;
    gn_finalize_kernel<<<fgrid, blk, 0, stream>>>(B.mrx, P[6], P[7], B.scx, B.shx, OC);
    gn_finalize_kernel<<<fgrid, blk, 0, stream>>>(B.mry, P[12], P[13], B.scy, B.shy, OC);
    gemm128_kernel<<<dim3(400, OC / 128), blk, 0, stream>>>(
        B.abuf, B.bqx, B.bqy, OC, B.wf, 3 * OC, OC, P[15],
        B.scx, B.shx, B.scy, B.shy, B.hout, 1);
}

extern "C" void kernel_launch(void* const* d_in, const int* in_sizes, int n_in,
                              void* d_out, int out_size, void* d_ws, size_t ws_size,
                              hipStream_t stream) {
    const float* x = (const float*)d_in[0];
    const float* P1[16];
    const float* P2[16];
    for (int i = 0; i < 16; i++) {
        P1[i] = (const float*)d_in[1 + i];
        P2[i] = (const float*)d_in[17 + i];
    }
    char* base = (char*)d_ws;
    size_t off = 0;
    auto alloc = [&](size_t bytes) -> char* {
        off = (off + 255) & ~(size_t)255;
        char* p = base + off;
        off += bytes;
        return p;
    };
    ushort* xh   = (ushort*)alloc((size_t)B_ * HW * 256 * 2);
    ushort* abuf = (ushort*)alloc((size_t)B_ * HW * 256 * 2);
    ushort* bqx  = (ushort*)alloc((size_t)B_ * HW * 256 * 2);
    ushort* bqy  = (ushort*)alloc((size_t)B_ * HW * 256 * 2);
    ushort* h1   = (ushort*)alloc((size_t)B_ * HW * 128 * 2);
    float*  off4 = (float*)alloc((size_t)B_ * 4 * HW * 4);
    float*  mrx  = (float*)alloc(4096);
    float*  mry  = (float*)alloc(4096);
    float*  scx  = (float*)alloc(B_ * 256 * 4);
    float*  shx  = (float*)alloc(B_ * 256 * 4);
    float*  scy  = (float*)alloc(B_ * 256 * 4);
    float*  shy  = (float*)alloc(B_ * 256 * 4);
    ushort* wc1  = (ushort*)alloc((size_t)128 * 9 * 256 * 2);
    ushort* wc2  = (ushort*)alloc((size_t)256 * 9 * 128 * 2);
    ushort* wdx1 = (ushort*)alloc((size_t)128 * 3 * 256 * 2);
    ushort* wdy1 = (ushort*)alloc((size_t)128 * 3 * 256 * 2);
    ushort* wdx2 = (ushort*)alloc((size_t)256 * 3 * 128 * 2);
    ushort* wdy2 = (ushort*)alloc((size_t)256 * 3 * 128 * 2);
    ushort* wf1  = (ushort*)alloc((size_t)128 * 384 * 2);
    ushort* wf2  = (ushort*)alloc((size_t)256 * 768 * 2);
    ushort* wo1  = (ushort*)alloc((size_t)32 * 9 * 256 * 2);
    ushort* wo2  = (ushort*)alloc((size_t)32 * 9 * 128 * 2);
    float*  bo1  = (float*)alloc(32 * 4);
    float*  bo2  = (float*)alloc(32 * 4);

    dim3 blk(256);
    auto wp = [&](const float* s, ushort* d, int OC, int CIN, int T) {
        int n = OC * CIN * T;
        wprep_kernel<<<(n + 255) / 256, blk, 0, stream>>>(s, d, OC, CIN, T);
    };
    wp(P1[0], wc1, 128, 256, 9);
    wp(P1[4], wdx1, 128, 256, 3);
    wp(P1[10], wdy1, 128, 256, 3);
    wp(P1[14], wf1, 128, 384, 1);
    wp(P2[0], wc2, 256, 128, 9);
    wp(P2[4], wdx2, 256, 128, 3);
    wp(P2[10], wdy2, 256, 128, 3);
    wp(P2[14], wf2, 256, 768, 1);
    wprep_off_kernel<<<(32 * 9 * 256 + 255) / 256, blk, 0, stream>>>(
        P1[2], P1[3], P1[8], P1[9], wo1, bo1, 256);
    wprep_off_kernel<<<(32 * 9 * 128 + 255) / 256, blk, 0, stream>>>(
        P2[2], P2[3], P2[8], P2[9], wo2, bo2, 128);

    transpose_x_kernel<<<dim3(100, 4, B_), blk, 0, stream>>>(x, xh, 256);

    BlkBuf B1 = {xh, abuf, bqx, bqy, h1, off4, mrx, mry, scx, shx, scy, shy,
                 bo1, wc1, wdx1, wdy1, wf1, wo1};
    run_block(B1, 256, 128, P1, stream);

    ushort* h2 = xh;  // reuse slab (xh dead after block1)
    BlkBuf B2 = {h1, abuf, bqx, bqy, h2, off4, mrx, mry, scx, shx, scy, shy,
                 bo2, wc2, wdx2, wdy2, wf2, wo2};
    run_block(B2, 128, 256, P2, stream);

    final_add_kernel<<<dim3(100, 4, B_), blk, 0, stream>>>(x, h2, (float*)d_out, 256);
}

// Round 5
// 661.978 us; speedup vs baseline: 6.7098x; 1.0620x over previous
//
#include <hip/hip_runtime.h>
#include <cstddef>

#define B_   8
#define H_   80
#define W_   80
#define HW   6400

typedef __attribute__((ext_vector_type(8)))  short short8;
typedef __attribute__((ext_vector_type(16))) float f32x16;

__device__ __forceinline__ float bf2f(ushort u) {
    return __uint_as_float(((unsigned)u) << 16);
}
__device__ __forceinline__ ushort f2bf(float f) {
    unsigned u = __float_as_uint(f);
    u += 0x7FFF + ((u >> 16) & 1);   // RNE
    return (ushort)(u >> 16);
}
__device__ __forceinline__ f32x16 mfma16(short8 a, short8 b, f32x16 c) {
    return __builtin_amdgcn_mfma_f32_32x32x16_bf16(a, b, c, 0, 0, 0);
}
// async global->LDS, 16B per lane (wave-uniform base + lane*16)
__device__ __forceinline__ void async16(const void* g, void* l) {
    __builtin_amdgcn_global_load_lds(
        (const __attribute__((address_space(1))) unsigned int*)g,
        (__attribute__((address_space(3))) unsigned int*)l, 16, 0, 0);
}
// swizzled fragment address in 64-ushort-stride LDS tile
__device__ __forceinline__ const ushort* frag_ptr(const ushort* sbuf, int row, int c8l) {
    return sbuf + row * 64 + ((c8l ^ (row & 7)) << 3);
}

// ---------------------------------------------------------------------------
// x fp32 NCHW -> xh bf16 NHWC.  grid (HW/64, C/64, B)
// ---------------------------------------------------------------------------
__global__ __launch_bounds__(256) void transpose_x_kernel(
    const float* __restrict__ x, ushort* __restrict__ xh, int C) {
    __shared__ float s[64][65];
    int hw0 = blockIdx.x * 64, c0 = blockIdx.y * 64, b = blockIdx.z;
    int t = threadIdx.x;
    int hl = t & 63, cq = t >> 6;
    #pragma unroll
    for (int i = 0; i < 16; i++) {
        int cl = cq * 16 + i;
        s[cl][hl] = x[((size_t)(b * C + c0 + cl)) * HW + hw0 + hl];
    }
    __syncthreads();
    int cl = t & 63, hq = t >> 6;
    #pragma unroll
    for (int i = 0; i < 16; i++) {
        int hl2 = hq * 16 + i;
        xh[((size_t)(b * HW + hw0 + hl2)) * C + c0 + cl] = f2bf(s[cl][hl2]);
    }
}

// ---------------------------------------------------------------------------
// final: d_out[b][c][hw] = x[b][c][hw] + h2[b][hw][c]
// ---------------------------------------------------------------------------
__global__ __launch_bounds__(256) void final_add_kernel(
    const float* __restrict__ x, const ushort* __restrict__ h2,
    float* __restrict__ out, int C) {
    __shared__ float s[64][65];
    int hw0 = blockIdx.x * 64, c0 = blockIdx.y * 64, b = blockIdx.z;
    int t = threadIdx.x;
    int cl = t & 63, hq = t >> 6;
    #pragma unroll
    for (int i = 0; i < 16; i++) {
        int hl = hq * 16 + i;
        s[cl][hl] = bf2f(h2[((size_t)(b * HW + hw0 + hl)) * C + c0 + cl]);
    }
    __syncthreads();
    int hl = t & 63, cq = t >> 6;
    #pragma unroll
    for (int i = 0; i < 16; i++) {
        int cl2 = cq * 16 + i;
        size_t o = ((size_t)(b * C + c0 + cl2)) * HW + hw0 + hl;
        out[o] = x[o] + s[cl2][hl];
    }
}

// ---------------------------------------------------------------------------
// Weight prep: src fp32 [OC][CIN][T] -> dst bf16 [OC][T][CIN]
// ---------------------------------------------------------------------------
__global__ void wprep_kernel(const float* __restrict__ src,
                             ushort* __restrict__ dst, int OC, int CIN, int T) {
    int idx = blockIdx.x * 256 + threadIdx.x;
    if (idx >= OC * CIN * T) return;
    int oc = idx / (CIN * T);
    int r = idx - oc * CIN * T;
    int ci = r / T, t_ = r - ci * T;
    dst[((size_t)oc * T + t_) * CIN + ci] = f2bf(src[idx]);
}

// ---------------------------------------------------------------------------
// Offset weight prep: pack 4 wanted channels (+28 zero pads) into [32][9][CIN]
// ---------------------------------------------------------------------------
__global__ void wprep_off_kernel(const float* __restrict__ wx_,
                                 const float* __restrict__ bx_,
                                 const float* __restrict__ wy_,
                                 const float* __restrict__ by_,
                                 ushort* __restrict__ dst,
                                 float* __restrict__ bdst, int CIN) {
    int idx = blockIdx.x * 256 + threadIdx.x;
    if (idx < 4) {
        const int chs[4] = {0, 2, 3, 5};
        bdst[idx] = (idx < 2) ? bx_[chs[idx]] : by_[chs[idx]];
    }
    if (idx >= 32 * 9 * CIN) return;
    int oc = idx / (9 * CIN);
    int r = idx - oc * 9 * CIN;
    int tap = r / CIN, ci = r - tap * CIN;
    float v = 0.f;
    if (oc < 4) {
        const int chs[4] = {0, 2, 3, 5};
        const float* src = (oc < 2) ? wx_ : wy_;
        v = src[((size_t)chs[oc] * CIN + ci) * 9 + tap];
    }
    dst[idx] = f2bf(v);
}

// ---------------------------------------------------------------------------
// Offset conv via MFMA: 16x16 spatial tile, N=32 (4 real oc), tanh epilogue.
// grid (25, B)
// ---------------------------------------------------------------------------
__global__ __launch_bounds__(256, 2) void off_conv_mfma_kernel(
    const ushort* __restrict__ xh, const ushort* __restrict__ wB,
    const float* __restrict__ bias, float* __restrict__ off4, int CIN) {
    __shared__ ushort s_x[18 * 18 * 40];
    __shared__ ushort s_w[288 * 32];
    int tid = threadIdx.x;
    int ty0 = (blockIdx.x / 5) * 16, tx0 = (blockIdx.x % 5) * 16;
    int b = blockIdx.y;
    int lane = tid & 63, wid = tid >> 6;
    int l31 = lane & 31, kg = lane >> 5;
    int pym[2], pxm[2];
    #pragma unroll
    for (int mf = 0; mf < 2; mf++) {
        int p = wid * 64 + mf * 32 + l31;
        pym[mf] = p >> 4; pxm[mf] = p & 15;
    }
    f32x16 acc[2] = {};
    for (int c0 = 0; c0 < CIN; c0 += 32) {
        __syncthreads();
        for (int u = tid; u < 1296; u += 256) {
            int pid = u >> 2, ci8 = u & 3;
            int r = pid / 18, c = pid - r * 18;
            int gy = ty0 + r - 1, gx = tx0 + c - 1;
            uint4 v = make_uint4(0, 0, 0, 0);
            if ((unsigned)gy < H_ && (unsigned)gx < W_)
                v = *(const uint4*)(xh + ((size_t)(b * HW + gy * W_ + gx)) * CIN + c0 + ci8 * 8);
            *(uint4*)(s_x + pid * 40 + ci8 * 8) = v;
        }
        // weights via async DMA: 1152 slots of 16B, 18 wave-calls
        for (int cc = wid; cc < 18; cc += 4) {
            int s = cc * 64 + lane;
            int R = s >> 2, ci8p = s & 3;
            int ci8l = ci8p ^ (R & 3);
            int tap = R >> 5, oc = R & 31;
            async16(wB + ((size_t)oc * 9 + tap) * CIN + c0 + ci8l * 8, s_w + s * 8);
        }
        __syncthreads();
        #pragma unroll
        for (int tap = 0; tap < 9; tap++) {
            int dy = tap / 3, dx = tap - dy * 3;
            const ushort* swt = s_w + (tap * 32 + l31) * 32;
            #pragma unroll
            for (int ks = 0; ks < 2; ks++) {
                int blk = (ks * 2 + kg) ^ (l31 & 3);
                short8 bfr = *(const short8*)(swt + blk * 8);
                #pragma unroll
                for (int mf = 0; mf < 2; mf++) {
                    int pix = (pym[mf] + dy) * 18 + (pxm[mf] + dx);
                    short8 afr = *(const short8*)(s_x + pix * 40 + ks * 16 + kg * 8);
                    acc[mf] = mfma16(afr, bfr, acc[mf]);
                }
            }
        }
    }
    int oc = l31;
    if (oc < 4) {
        float bb = bias[oc];
        #pragma unroll
        for (int mf = 0; mf < 2; mf++) {
            #pragma unroll
            for (int reg = 0; reg < 16; reg++) {
                int row = (reg & 3) + 8 * (reg >> 2) + 4 * kg;
                int p = wid * 64 + mf * 32 + row;
                int y = ty0 + (p >> 4), x = tx0 + (p & 15);
                off4[((size_t)b * 4 + oc) * HW + y * W_ + x] = tanhf(acc[mf][reg] + bb);
            }
        }
    }
}

// ---------------------------------------------------------------------------
// Implicit conv3x3 + bias + SiLU via MFMA.  16x16 tile, BN=64 oc.
// Weights staged via async global->LDS DMA.  grid (25, OC/64, B)
// ---------------------------------------------------------------------------
__global__ __launch_bounds__(256, 2) void conv3x3_mfma_kernel(
    const ushort* __restrict__ xh, const ushort* __restrict__ wB,
    const float* __restrict__ bias, ushort* __restrict__ out,
    int CIN, int OC) {
    __shared__ ushort s_x[18 * 18 * 40];
    __shared__ ushort s_w[576 * 32];
    int tid = threadIdx.x;
    int ty0 = (blockIdx.x / 5) * 16, tx0 = (blockIdx.x % 5) * 16;
    int n0 = blockIdx.y * 64, b = blockIdx.z;
    int lane = tid & 63, wid = tid >> 6;
    int l31 = lane & 31, kg = lane >> 5;
    int wm = wid >> 1, wn = wid & 1;
    int pym[4], pxm[4];
    #pragma unroll
    for (int mf = 0; mf < 4; mf++) {
        int p = wm * 128 + mf * 32 + l31;
        pym[mf] = p >> 4; pxm[mf] = p & 15;
    }
    f32x16 acc[4] = {};
    for (int c0 = 0; c0 < CIN; c0 += 32) {
        __syncthreads();
        for (int u = tid; u < 1296; u += 256) {
            int pid = u >> 2, ci8 = u & 3;
            int r = pid / 18, c = pid - r * 18;
            int gy = ty0 + r - 1, gx = tx0 + c - 1;
            uint4 v = make_uint4(0, 0, 0, 0);
            if ((unsigned)gy < H_ && (unsigned)gx < W_)
                v = *(const uint4*)(xh + ((size_t)(b * HW + gy * W_ + gx)) * CIN + c0 + ci8 * 8);
            *(uint4*)(s_x + pid * 40 + ci8 * 8) = v;
        }
        // weights: 2304 slots of 16B = 36 wave-calls (9 per wave)
        #pragma unroll
        for (int j = 0; j < 9; j++) {
            int s = (wid * 9 + j) * 64 + lane;
            int R = s >> 2, ci8p = s & 3;
            int ci8l = ci8p ^ (R & 3);
            int tap = R >> 6, oc = R & 63;
            async16(wB + ((size_t)(n0 + oc) * 9 + tap) * CIN + c0 + ci8l * 8,
                    s_w + s * 8);
        }
        __syncthreads();
        #pragma unroll
        for (int tap = 0; tap < 9; tap++) {
            int dy = tap / 3, dx = tap - dy * 3;
            const ushort* swt = s_w + (tap * 64 + wn * 32 + l31) * 32;
            #pragma unroll
            for (int ks = 0; ks < 2; ks++) {
                int blk = (ks * 2 + kg) ^ (l31 & 3);
                short8 bfr = *(const short8*)(swt + blk * 8);
                #pragma unroll
                for (int mf = 0; mf < 4; mf++) {
                    int pix = (pym[mf] + dy) * 18 + (pxm[mf] + dx);
                    short8 afr = *(const short8*)(s_x + pix * 40 + ks * 16 + kg * 8);
                    acc[mf] = mfma16(afr, bfr, acc[mf]);
                }
            }
        }
    }
    int oc = n0 + wn * 32 + l31;
    float bb = bias[oc];
    #pragma unroll
    for (int mf = 0; mf < 4; mf++) {
        #pragma unroll
        for (int reg = 0; reg < 16; reg++) {
            int row = (reg & 3) + 8 * (reg >> 2) + 4 * kg;
            int p = wm * 128 + mf * 32 + row;
            int y = ty0 + (p >> 4), x = tx0 + (p & 15);
            float v = acc[mf][reg] + bb;
            v = v / (1.f + expf(-v));
            out[((size_t)(b * HW + y * W_ + x)) * OC + oc] = f2bf(v);
        }
    }
}

// ---------------------------------------------------------------------------
// Snake-conv GEMM with fused bilinear gather.  Both morphs in one launch
// (blockIdx.z).  B staged via async DMA; A gathered+lerped (VGPR) into
// swizzled LDS.  grid (400, OC/128, 2)
// ---------------------------------------------------------------------------
__global__ __launch_bounds__(256, 4) void dsc_gemm_kernel(
    const ushort* __restrict__ xh, const float* __restrict__ off4,
    const ushort* __restrict__ Bwx, const float* __restrict__ biasx,
    ushort* __restrict__ outx,
    const ushort* __restrict__ Bwy, const float* __restrict__ biasy,
    ushort* __restrict__ outy, int CIN, int OC) {
    __shared__ ushort s_a[128 * 64];
    __shared__ ushort s_b[128 * 64];
    __shared__ int   s_i0[3][128];
    __shared__ int   s_i1[3][128];
    __shared__ float s_wl[3][128];
    int tid = threadIdx.x;
    int morph = blockIdx.z;
    const ushort* Bw = morph ? Bwy : Bwx;
    const float* bias = morph ? biasy : biasx;
    ushort* out = morph ? outy : outx;
    int m0 = blockIdx.x * 128, n0 = blockIdx.y * 128;
    int b = m0 / HW, hw0 = m0 - b * HW;    // 6400 % 128 == 0
    for (int u = tid; u < 384; u += 256) {
        int k3 = u >> 7, r = u & 127;
        int hw = hw0 + r;
        int h = hw / W_, w = hw - h * W_;
        float bend = 0.f;
        if (k3 != 1) {
            int mp = (morph ? 2 : 0) + (k3 >> 1);
            bend = off4[((size_t)b * 4 + mp) * HW + hw];
        }
        int i0, i1; float wl;
        if (morph == 0) {
            float ys = fminf(fmaxf((float)h + bend, 0.f), 79.f);
            float y0f = floorf(ys); wl = ys - y0f;
            int y0 = (int)y0f, y1 = min(y0 + 1, 79);
            int xk = min(max(w + k3 - 1, 0), 79);
            i0 = y0 * W_ + xk; i1 = y1 * W_ + xk;
        } else {
            float xs = fminf(fmaxf((float)w + bend, 0.f), 79.f);
            float x0f = floorf(xs); wl = xs - x0f;
            int x0 = (int)x0f, x1 = min(x0 + 1, 79);
            int yk = min(max(h + k3 - 1, 0), 79);
            i0 = yk * W_ + x0; i1 = yk * W_ + x1;
        }
        s_i0[k3][r] = i0; s_i1[k3][r] = i1; s_wl[k3][r] = wl;
    }
    int lane = tid & 63, wid = tid >> 6;
    int l31 = lane & 31, kg = lane >> 5;
    int wm = wid >> 1, wn = wid & 1;
    f32x16 acc[2][2] = {};
    int K = 3 * CIN, nk = K >> 6;
    const ushort* xb = xh + (size_t)b * HW * CIN;
    for (int kc = 0; kc < nk; kc++) {
        int kg64 = kc << 6;
        int k3 = kg64 / CIN;              // uniform per kc (64 | CIN)
        int cioff = kg64 - k3 * CIN;
        __syncthreads();
        // B: async DMA, 16 wave-calls
        #pragma unroll
        for (int j = 0; j < 4; j++) {
            int s = (wid * 4 + j) * 64 + lane;
            int r = s >> 3, c8p = s & 7;
            int c8l = c8p ^ (r & 7);
            async16(Bw + (size_t)(n0 + r) * K + kg64 + c8l * 8, s_b + s * 8);
        }
        // A: gather + lerp (VGPR), swizzled write
        #pragma unroll
        for (int i = 0; i < 4; i++) {
            int s = i * 256 + tid;
            int r = s >> 3, c8p = s & 7;
            int c8l = c8p ^ (r & 7);
            int ci = cioff + c8l * 8;
            float wl = s_wl[k3][r];
            uint4 u0 = *(const uint4*)(xb + (size_t)s_i0[k3][r] * CIN + ci);
            uint4 u1 = *(const uint4*)(xb + (size_t)s_i1[k3][r] * CIN + ci);
            const ushort* p0 = (const ushort*)&u0;
            const ushort* p1 = (const ushort*)&u1;
            ushort tv[8];
            #pragma unroll
            for (int j = 0; j < 8; j++) {
                float f0 = bf2f(p0[j]);
                tv[j] = f2bf(f0 + (bf2f(p1[j]) - f0) * wl);
            }
            *(uint4*)(s_a + s * 8) = *(uint4*)tv;
        }
        __syncthreads();
        #pragma unroll
        for (int ks = 0; ks < 4; ks++) {
            int c8l = ks * 2 + kg;
            short8 af0 = *(const short8*)frag_ptr(s_a, wm * 64 + l31, c8l);
            short8 af1 = *(const short8*)frag_ptr(s_a, wm * 64 + 32 + l31, c8l);
            short8 bf0 = *(const short8*)frag_ptr(s_b, wn * 64 + l31, c8l);
            short8 bf1 = *(const short8*)frag_ptr(s_b, wn * 64 + 32 + l31, c8l);
            acc[0][0] = mfma16(af0, bf0, acc[0][0]);
            acc[0][1] = mfma16(af0, bf1, acc[0][1]);
            acc[1][0] = mfma16(af1, bf0, acc[1][0]);
            acc[1][1] = mfma16(af1, bf1, acc[1][1]);
        }
    }
    #pragma unroll
    for (int nf = 0; nf < 2; nf++) {
        int n = n0 + wn * 64 + nf * 32 + l31;
        float bb = bias[n];
        #pragma unroll
        for (int mf = 0; mf < 2; mf++) {
            #pragma unroll
            for (int reg = 0; reg < 16; reg++) {
                int row = (reg & 3) + 8 * (reg >> 2) + 4 * kg;
                int m = m0 + wm * 64 + mf * 32 + row;
                out[(size_t)m * OC + n] = f2bf(acc[mf][nf][reg] + bb);
            }
        }
    }
}

// ---------------------------------------------------------------------------
// Pure 128x128 MFMA GEMM over concat-A (up to 3 parts), all staging via
// async global->LDS DMA.  SiLU epilogue.  grid (400, N/128)
// ---------------------------------------------------------------------------
__global__ __launch_bounds__(256, 4) void gemm128_kernel(
    const ushort* __restrict__ a0, const ushort* __restrict__ a1,
    const ushort* __restrict__ a2, int part_k,
    const ushort* __restrict__ Bw, int K, int N,
    const float* __restrict__ bias, ushort* __restrict__ out, int epi_silu) {
    __shared__ ushort s_a[128 * 64];
    __shared__ ushort s_b[128 * 64];
    int tid = threadIdx.x;
    int m0 = blockIdx.x * 128, n0 = blockIdx.y * 128;
    int lane = tid & 63, wid = tid >> 6;
    int l31 = lane & 31, kg = lane >> 5;
    int wm = wid >> 1, wn = wid & 1;
    f32x16 acc[2][2] = {};
    int nk = K >> 6;
    for (int kc = 0; kc < nk; kc++) {
        int kg64 = kc << 6;
        int part = kg64 / part_k;
        int koff = kg64 - part * part_k;
        const ushort* ap = (part == 0) ? a0 : (part == 1 ? a1 : a2);
        __syncthreads();
        #pragma unroll
        for (int j = 0; j < 4; j++) {
            int s = (wid * 4 + j) * 64 + lane;
            int r = s >> 3, c8p = s & 7;
            int c8l = c8p ^ (r & 7);
            async16(ap + (size_t)(m0 + r) * part_k + koff + c8l * 8, s_a + s * 8);
            async16(Bw + (size_t)(n0 + r) * K + kg64 + c8l * 8, s_b + s * 8);
        }
        __syncthreads();
        #pragma unroll
        for (int ks = 0; ks < 4; ks++) {
            int c8l = ks * 2 + kg;
            short8 af0 = *(const short8*)frag_ptr(s_a, wm * 64 + l31, c8l);
            short8 af1 = *(const short8*)frag_ptr(s_a, wm * 64 + 32 + l31, c8l);
            short8 bf0 = *(const short8*)frag_ptr(s_b, wn * 64 + l31, c8l);
            short8 bf1 = *(const short8*)frag_ptr(s_b, wn * 64 + 32 + l31, c8l);
            acc[0][0] = mfma16(af0, bf0, acc[0][0]);
            acc[0][1] = mfma16(af0, bf1, acc[0][1]);
            acc[1][0] = mfma16(af1, bf0, acc[1][0]);
            acc[1][1] = mfma16(af1, bf1, acc[1][1]);
        }
    }
    #pragma unroll
    for (int nf = 0; nf < 2; nf++) {
        int n = n0 + wn * 64 + nf * 32 + l31;
        float bb = bias[n];
        #pragma unroll
        for (int mf = 0; mf < 2; mf++) {
            #pragma unroll
            for (int reg = 0; reg < 16; reg++) {
                int row = (reg & 3) + 8 * (reg >> 2) + 4 * kg;
                int m = m0 + wm * 64 + mf * 32 + row;
                float v = acc[mf][nf][reg] + bb;
                if (epi_silu) v = v / (1.f + expf(-v));
                out[(size_t)m * N + n] = f2bf(v);
            }
        }
    }
}

// ---------------------------------------------------------------------------
// GN stats from bf16 NHWC: grid (B*G, 2) -- y picks bqx/bqy
// ---------------------------------------------------------------------------
__global__ __launch_bounds__(256) void gn_stats_kernel(
    const ushort* __restrict__ srcx, const ushort* __restrict__ srcy,
    float* __restrict__ mrx, float* __restrict__ mry, int C) {
    const ushort* src = blockIdx.y ? srcy : srcx;
    float* mr = blockIdx.y ? mry : mrx;
    int G = C >> 2;
    int bg = blockIdx.x;
    int b = bg / G, g = bg - b * G;
    float s = 0.f, sq = 0.f;
    for (int hw = threadIdx.x; hw < HW; hw += 256) {
        const ushort* p = src + ((size_t)(b * HW + hw)) * C + g * 4;
        ushort4 u = *(const ushort4*)p;
        float v0 = bf2f(u.x), v1 = bf2f(u.y), v2 = bf2f(u.z), v3 = bf2f(u.w);
        s += v0 + v1 + v2 + v3;
        sq += v0 * v0 + v1 * v1 + v2 * v2 + v3 * v3;
    }
    #pragma unroll
    for (int off = 32; off; off >>= 1) {
        s += __shfl_down(s, off);
        sq += __shfl_down(sq, off);
    }
    __shared__ float sh[2][4];
    int wid = threadIdx.x >> 6, lane = threadIdx.x & 63;
    if (lane == 0) { sh[0][wid] = s; sh[1][wid] = sq; }
    __syncthreads();
    if (threadIdx.x == 0) {
        s = sh[0][0] + sh[0][1] + sh[0][2] + sh[0][3];
        sq = sh[1][0] + sh[1][1] + sh[1][2] + sh[1][3];
        float mean = s / (4.f * HW);
        float var = sq / (4.f * HW) - mean * mean;
        mr[bg * 2] = mean;
        mr[bg * 2 + 1] = rsqrtf(var + 1e-5f);
    }
}

// ---------------------------------------------------------------------------
// GN finalize: scale/shift per (b,c)
// ---------------------------------------------------------------------------
__global__ void gn_finalize_kernel(const float* __restrict__ mr,
                                   const float* __restrict__ gamma,
                                   const float* __restrict__ beta,
                                   float* __restrict__ sc, float* __restrict__ sh,
                                   int C) {
    int idx = blockIdx.x * 256 + threadIdx.x;
    if (idx >= B_ * C) return;
    int b = idx / C, c = idx - b * C;
    int g = c >> 2, G = C >> 2;
    float mean = mr[(b * G + g) * 2];
    float rs = mr[(b * G + g) * 2 + 1];
    float s = rs * gamma[c];
    sc[idx] = s;
    sh[idx] = beta[c] - mean * s;
}

// ---------------------------------------------------------------------------
// GN apply + ReLU, in place on bf16 NHWC.  grid (B*HW*C/2048, 2)
// ---------------------------------------------------------------------------
__global__ __launch_bounds__(256) void gn_apply_kernel(
    ushort* __restrict__ bqx, ushort* __restrict__ bqy,
    const float* __restrict__ scx, const float* __restrict__ shx,
    const float* __restrict__ scy, const float* __restrict__ shy, int C) {
    ushort* bq = blockIdx.y ? bqy : bqx;
    const float* sc = blockIdx.y ? scy : scx;
    const float* sh = blockIdx.y ? shy : shx;
    size_t e = ((size_t)blockIdx.x * 256 + threadIdx.x) * 8;
    int c = (int)(e % C);
    int b = (int)(e / ((size_t)HW * C));
    const float* scb = sc + (size_t)b * C + c;
    const float* shb = sh + (size_t)b * C + c;
    uint4 v = *(const uint4*)(bq + e);
    const ushort* sv = (const ushort*)&v;
    ushort tv[8];
    #pragma unroll
    for (int j = 0; j < 8; j++)
        tv[j] = f2bf(fmaxf(bf2f(sv[j]) * scb[j] + shb[j], 0.f));
    *(uint4*)(bq + e) = *(uint4*)tv;
}

// ---------------------------------------------------------------------------
// Host orchestration
// ---------------------------------------------------------------------------
struct BlkBuf {
    ushort *xh, *abuf, *bqx, *bqy, *hout;
    float *off4, *mrx, *mry, *scx, *shx, *scy, *shy, *boff;
    ushort *wc, *wdx, *wdy, *wf, *woff;
};

static void run_block(const BlkBuf& B, int CIN, int OC,
                      const float* const* P, hipStream_t stream) {
    dim3 blk(256);
    off_conv_mfma_kernel<<<dim3(25, B_), blk, 0, stream>>>(
        B.xh, B.woff, B.boff, B.off4, CIN);
    conv3x3_mfma_kernel<<<dim3(25, OC / 64, B_), blk, 0, stream>>>(
        B.xh, B.wc, P[1], B.abuf, CIN, OC);
    dsc_gemm_kernel<<<dim3(400, OC / 128, 2), blk, 0, stream>>>(
        B.xh, B.off4, B.wdx, P[5], B.bqx, B.wdy, P[11], B.bqy, CIN, OC);
    int G = OC / 4;
    gn_stats_kernel<<<dim3(B_ * G, 2), blk, 0, stream>>>(
        B.bqx, B.bqy, B.mrx, B.mry, OC);
    int fgrid = (B_ * OC + 255) / 256;
    gn_finalize_kernel<<<fgrid, blk, 0, stream>>>(B.mrx, P[6], P[7], B.scx, B.shx, OC);
    gn_finalize_kernel<<<fgrid, blk, 0, stream>>>(B.mry, P[12], P[13], B.scy, B.shy, OC);
    gn_apply_kernel<<<dim3((B_ * HW * OC) / 2048, 2), blk, 0, stream>>>(
        B.bqx, B.bqy, B.scx, B.shx, B.scy, B.shy, OC);
    gemm128_kernel<<<dim3(400, OC / 128), blk, 0, stream>>>(
        B.abuf, B.bqx, B.bqy, OC, B.wf, 3 * OC, OC, P[15], B.hout, 1);
}

extern "C" void kernel_launch(void* const* d_in, const int* in_sizes, int n_in,
                              void* d_out, int out_size, void* d_ws, size_t ws_size,
                              hipStream_t stream) {
    const float* x = (const float*)d_in[0];
    const float* P1[16];
    const float* P2[16];
    for (int i = 0; i < 16; i++) {
        P1[i] = (const float*)d_in[1 + i];
        P2[i] = (const float*)d_in[17 + i];
    }
    char* base = (char*)d_ws;
    size_t off = 0;
    auto alloc = [&](size_t bytes) -> char* {
        off = (off + 255) & ~(size_t)255;
        char* p = base + off;
        off += bytes;
        return p;
    };
    ushort* xh   = (ushort*)alloc((size_t)B_ * HW * 256 * 2);
    ushort* abuf = (ushort*)alloc((size_t)B_ * HW * 256 * 2);
    ushort* bqx  = (ushort*)alloc((size_t)B_ * HW * 256 * 2);
    ushort* bqy  = (ushort*)alloc((size_t)B_ * HW * 256 * 2);
    ushort* h1   = (ushort*)alloc((size_t)B_ * HW * 128 * 2);
    float*  off4 = (float*)alloc((size_t)B_ * 4 * HW * 4);
    float*  mrx  = (float*)alloc(4096);
    float*  mry  = (float*)alloc(4096);
    float*  scx  = (float*)alloc(B_ * 256 * 4);
    float*  shx  = (float*)alloc(B_ * 256 * 4);
    float*  scy  = (float*)alloc(B_ * 256 * 4);
    float*  shy  = (float*)alloc(B_ * 256 * 4);
    ushort* wc1  = (ushort*)alloc((size_t)128 * 9 * 256 * 2);
    ushort* wc2  = (ushort*)alloc((size_t)256 * 9 * 128 * 2);
    ushort* wdx1 = (ushort*)alloc((size_t)128 * 3 * 256 * 2);
    ushort* wdy1 = (ushort*)alloc((size_t)128 * 3 * 256 * 2);
    ushort* wdx2 = (ushort*)alloc((size_t)256 * 3 * 128 * 2);
    ushort* wdy2 = (ushort*)alloc((size_t)256 * 3 * 128 * 2);
    ushort* wf1  = (ushort*)alloc((size_t)128 * 384 * 2);
    ushort* wf2  = (ushort*)alloc((size_t)256 * 768 * 2);
    ushort* wo1  = (ushort*)alloc((size_t)32 * 9 * 256 * 2);
    ushort* wo2  = (ushort*)alloc((size_t)32 * 9 * 128 * 2);
    float*  bo1  = (float*)alloc(32 * 4);
    float*  bo2  = (float*)alloc(32 * 4);

    dim3 blk(256);
    auto wp = [&](const float* s, ushort* d, int OC, int CIN, int T) {
        int n = OC * CIN * T;
        wprep_kernel<<<(n + 255) / 256, blk, 0, stream>>>(s, d, OC, CIN, T);
    };
    wp(P1[0], wc1, 128, 256, 9);
    wp(P1[4], wdx1, 128, 256, 3);
    wp(P1[10], wdy1, 128, 256, 3);
    wp(P1[14], wf1, 128, 384, 1);
    wp(P2[0], wc2, 256, 128, 9);
    wp(P2[4], wdx2, 256, 128, 3);
    wp(P2[10], wdy2, 256, 128, 3);
    wp(P2[14], wf2, 256, 768, 1);
    wprep_off_kernel<<<(32 * 9 * 256 + 255) / 256, blk, 0, stream>>>(
        P1[2], P1[3], P1[8], P1[9], wo1, bo1, 256);
    wprep_off_kernel<<<(32 * 9 * 128 + 255) / 256, blk, 0, stream>>>(
        P2[2], P2[3], P2[8], P2[9], wo2, bo2, 128);

    transpose_x_kernel<<<dim3(100, 4, B_), blk, 0, stream>>>(x, xh, 256);

    BlkBuf B1 = {xh, abuf, bqx, bqy, h1, off4, mrx, mry, scx, shx, scy, shy,
                 bo1, wc1, wdx1, wdy1, wf1, wo1};
    run_block(B1, 256, 128, P1, stream);

    ushort* h2 = xh;  // reuse slab (xh dead after block1)
    BlkBuf B2 = {h1, abuf, bqx, bqy, h2, off4, mrx, mry, scx, shx, scy, shy,
                 bo2, wc2, wdx2, wdy2, wf2, wo2};
    run_block(B2, 128, 256, P2, stream);

    final_add_kernel<<<dim3(100, 4, B_), blk, 0, stream>>>(x, h2, (float*)d_out, 256);
}

// Round 6
// 583.587 us; speedup vs baseline: 7.6111x; 1.1343x over previous
//
#include <hip/hip_runtime.h>
#include <cstddef>

#define B_   8
#define H_   80
#define W_   80
#define HW   6400

typedef __attribute__((ext_vector_type(8)))  short short8;
typedef __attribute__((ext_vector_type(16))) float f32x16;

__device__ __forceinline__ float bf2f(ushort u) {
    return __uint_as_float(((unsigned)u) << 16);
}
__device__ __forceinline__ ushort f2bf(float f) {
    unsigned u = __float_as_uint(f);
    u += 0x7FFF + ((u >> 16) & 1);   // RNE
    return (ushort)(u >> 16);
}
__device__ __forceinline__ f32x16 mfma16(short8 a, short8 b, f32x16 c) {
    return __builtin_amdgcn_mfma_f32_32x32x16_bf16(a, b, c, 0, 0, 0);
}
// async global->LDS, 16B per lane (wave-uniform base + lane*16)
__device__ __forceinline__ void async16(const void* g, void* l) {
    __builtin_amdgcn_global_load_lds(
        (const __attribute__((address_space(1))) unsigned int*)g,
        (__attribute__((address_space(3))) unsigned int*)l, 16, 0, 0);
}
// swizzled fragment address in 64-ushort-stride LDS tile
__device__ __forceinline__ const ushort* frag_ptr(const ushort* sbuf, int row, int c8l) {
    return sbuf + row * 64 + ((c8l ^ (row & 7)) << 3);
}

// ---------------------------------------------------------------------------
// x fp32 NCHW -> xh bf16 NHWC.  grid (HW/64, C/64, B)
// ---------------------------------------------------------------------------
__global__ __launch_bounds__(256) void transpose_x_kernel(
    const float* __restrict__ x, ushort* __restrict__ xh, int C) {
    __shared__ float s[64][65];
    int hw0 = blockIdx.x * 64, c0 = blockIdx.y * 64, b = blockIdx.z;
    int t = threadIdx.x;
    int hl = t & 63, cq = t >> 6;
    #pragma unroll
    for (int i = 0; i < 16; i++) {
        int cl = cq * 16 + i;
        s[cl][hl] = x[((size_t)(b * C + c0 + cl)) * HW + hw0 + hl];
    }
    __syncthreads();
    int cl = t & 63, hq = t >> 6;
    #pragma unroll
    for (int i = 0; i < 16; i++) {
        int hl2 = hq * 16 + i;
        xh[((size_t)(b * HW + hw0 + hl2)) * C + c0 + cl] = f2bf(s[cl][hl2]);
    }
}

// ---------------------------------------------------------------------------
// final: d_out[b][c][hw] = x[b][c][hw] + h2[b][hw][c]
// ---------------------------------------------------------------------------
__global__ __launch_bounds__(256) void final_add_kernel(
    const float* __restrict__ x, const ushort* __restrict__ h2,
    float* __restrict__ out, int C) {
    __shared__ float s[64][65];
    int hw0 = blockIdx.x * 64, c0 = blockIdx.y * 64, b = blockIdx.z;
    int t = threadIdx.x;
    int cl = t & 63, hq = t >> 6;
    #pragma unroll
    for (int i = 0; i < 16; i++) {
        int hl = hq * 16 + i;
        s[cl][hl] = bf2f(h2[((size_t)(b * HW + hw0 + hl)) * C + c0 + cl]);
    }
    __syncthreads();
    int hl = t & 63, cq = t >> 6;
    #pragma unroll
    for (int i = 0; i < 16; i++) {
        int cl2 = cq * 16 + i;
        size_t o = ((size_t)(b * C + c0 + cl2)) * HW + hw0 + hl;
        out[o] = x[o] + s[cl2][hl];
    }
}

// ---------------------------------------------------------------------------
// Weight prep: src fp32 [OC][CIN][T] -> dst bf16 [OC][T][CIN]
// ---------------------------------------------------------------------------
__global__ void wprep_kernel(const float* __restrict__ src,
                             ushort* __restrict__ dst, int OC, int CIN, int T) {
    int idx = blockIdx.x * 256 + threadIdx.x;
    if (idx >= OC * CIN * T) return;
    int oc = idx / (CIN * T);
    int r = idx - oc * CIN * T;
    int ci = r / T, t_ = r - ci * T;
    dst[((size_t)oc * T + t_) * CIN + ci] = f2bf(src[idx]);
}

// ---------------------------------------------------------------------------
// Offset weight prep: pack 4 wanted channels (+28 zero pads) into [32][9][CIN]
// ---------------------------------------------------------------------------
__global__ void wprep_off_kernel(const float* __restrict__ wx_,
                                 const float* __restrict__ bx_,
                                 const float* __restrict__ wy_,
                                 const float* __restrict__ by_,
                                 ushort* __restrict__ dst,
                                 float* __restrict__ bdst, int CIN) {
    int idx = blockIdx.x * 256 + threadIdx.x;
    if (idx < 4) {
        const int chs[4] = {0, 2, 3, 5};
        bdst[idx] = (idx < 2) ? bx_[chs[idx]] : by_[chs[idx]];
    }
    if (idx >= 32 * 9 * CIN) return;
    int oc = idx / (9 * CIN);
    int r = idx - oc * 9 * CIN;
    int tap = r / CIN, ci = r - tap * CIN;
    float v = 0.f;
    if (oc < 4) {
        const int chs[4] = {0, 2, 3, 5};
        const float* src = (oc < 2) ? wx_ : wy_;
        v = src[((size_t)chs[oc] * CIN + ci) * 9 + tap];
    }
    dst[idx] = f2bf(v);
}

// ---------------------------------------------------------------------------
// Offset conv via MFMA: 16x16 spatial tile, N=32 (4 real oc), tanh epilogue.
// grid (25, B)
// ---------------------------------------------------------------------------
__global__ __launch_bounds__(256, 2) void off_conv_mfma_kernel(
    const ushort* __restrict__ xh, const ushort* __restrict__ wB,
    const float* __restrict__ bias, float* __restrict__ off4, int CIN) {
    __shared__ ushort s_x[18 * 18 * 40];
    __shared__ ushort s_w[288 * 32];
    int tid = threadIdx.x;
    int ty0 = (blockIdx.x / 5) * 16, tx0 = (blockIdx.x % 5) * 16;
    int b = blockIdx.y;
    int lane = tid & 63, wid = tid >> 6;
    int l31 = lane & 31, kg = lane >> 5;
    int pym[2], pxm[2];
    #pragma unroll
    for (int mf = 0; mf < 2; mf++) {
        int p = wid * 64 + mf * 32 + l31;
        pym[mf] = p >> 4; pxm[mf] = p & 15;
    }
    f32x16 acc[2] = {};
    for (int c0 = 0; c0 < CIN; c0 += 32) {
        __syncthreads();
        for (int u = tid; u < 1296; u += 256) {
            int pid = u >> 2, ci8 = u & 3;
            int r = pid / 18, c = pid - r * 18;
            int gy = ty0 + r - 1, gx = tx0 + c - 1;
            uint4 v = make_uint4(0, 0, 0, 0);
            if ((unsigned)gy < H_ && (unsigned)gx < W_)
                v = *(const uint4*)(xh + ((size_t)(b * HW + gy * W_ + gx)) * CIN + c0 + ci8 * 8);
            *(uint4*)(s_x + pid * 40 + ci8 * 8) = v;
        }
        // weights via async DMA: 1152 slots of 16B, 18 wave-calls
        for (int cc = wid; cc < 18; cc += 4) {
            int s = cc * 64 + lane;
            int R = s >> 2, ci8p = s & 3;
            int ci8l = ci8p ^ (R & 3);
            int tap = R >> 5, oc = R & 31;
            async16(wB + ((size_t)oc * 9 + tap) * CIN + c0 + ci8l * 8, s_w + s * 8);
        }
        __syncthreads();
        #pragma unroll
        for (int tap = 0; tap < 9; tap++) {
            int dy = tap / 3, dx = tap - dy * 3;
            const ushort* swt = s_w + (tap * 32 + l31) * 32;
            #pragma unroll
            for (int ks = 0; ks < 2; ks++) {
                int blk = (ks * 2 + kg) ^ (l31 & 3);
                short8 bfr = *(const short8*)(swt + blk * 8);
                #pragma unroll
                for (int mf = 0; mf < 2; mf++) {
                    int pix = (pym[mf] + dy) * 18 + (pxm[mf] + dx);
                    short8 afr = *(const short8*)(s_x + pix * 40 + ks * 16 + kg * 8);
                    acc[mf] = mfma16(afr, bfr, acc[mf]);
                }
            }
        }
    }
    int oc = l31;
    if (oc < 4) {
        float bb = bias[oc];
        #pragma unroll
        for (int mf = 0; mf < 2; mf++) {
            #pragma unroll
            for (int reg = 0; reg < 16; reg++) {
                int row = (reg & 3) + 8 * (reg >> 2) + 4 * kg;
                int p = wid * 64 + mf * 32 + row;
                int y = ty0 + (p >> 4), x = tx0 + (p & 15);
                off4[((size_t)b * 4 + oc) * HW + y * W_ + x] = tanhf(acc[mf][reg] + bb);
            }
        }
    }
}

// ---------------------------------------------------------------------------
// Implicit conv3x3 + bias + SiLU via MFMA.  16x16 tile, BN=64 oc.
// Weights staged via async global->LDS DMA.  grid (25, OC/64, B)
// ---------------------------------------------------------------------------
__global__ __launch_bounds__(256, 2) void conv3x3_mfma_kernel(
    const ushort* __restrict__ xh, const ushort* __restrict__ wB,
    const float* __restrict__ bias, ushort* __restrict__ out,
    int CIN, int OC) {
    __shared__ ushort s_x[18 * 18 * 40];
    __shared__ ushort s_w[576 * 32];
    int tid = threadIdx.x;
    int ty0 = (blockIdx.x / 5) * 16, tx0 = (blockIdx.x % 5) * 16;
    int n0 = blockIdx.y * 64, b = blockIdx.z;
    int lane = tid & 63, wid = tid >> 6;
    int l31 = lane & 31, kg = lane >> 5;
    int wm = wid >> 1, wn = wid & 1;
    int pym[4], pxm[4];
    #pragma unroll
    for (int mf = 0; mf < 4; mf++) {
        int p = wm * 128 + mf * 32 + l31;
        pym[mf] = p >> 4; pxm[mf] = p & 15;
    }
    f32x16 acc[4] = {};
    for (int c0 = 0; c0 < CIN; c0 += 32) {
        __syncthreads();
        for (int u = tid; u < 1296; u += 256) {
            int pid = u >> 2, ci8 = u & 3;
            int r = pid / 18, c = pid - r * 18;
            int gy = ty0 + r - 1, gx = tx0 + c - 1;
            uint4 v = make_uint4(0, 0, 0, 0);
            if ((unsigned)gy < H_ && (unsigned)gx < W_)
                v = *(const uint4*)(xh + ((size_t)(b * HW + gy * W_ + gx)) * CIN + c0 + ci8 * 8);
            *(uint4*)(s_x + pid * 40 + ci8 * 8) = v;
        }
        // weights: 2304 slots of 16B = 36 wave-calls (9 per wave)
        #pragma unroll
        for (int j = 0; j < 9; j++) {
            int s = (wid * 9 + j) * 64 + lane;
            int R = s >> 2, ci8p = s & 3;
            int ci8l = ci8p ^ (R & 3);
            int tap = R >> 6, oc = R & 63;
            async16(wB + ((size_t)(n0 + oc) * 9 + tap) * CIN + c0 + ci8l * 8,
                    s_w + s * 8);
        }
        __syncthreads();
        #pragma unroll
        for (int tap = 0; tap < 9; tap++) {
            int dy = tap / 3, dx = tap - dy * 3;
            const ushort* swt = s_w + (tap * 64 + wn * 32 + l31) * 32;
            #pragma unroll
            for (int ks = 0; ks < 2; ks++) {
                int blk = (ks * 2 + kg) ^ (l31 & 3);
                short8 bfr = *(const short8*)(swt + blk * 8);
                #pragma unroll
                for (int mf = 0; mf < 4; mf++) {
                    int pix = (pym[mf] + dy) * 18 + (pxm[mf] + dx);
                    short8 afr = *(const short8*)(s_x + pix * 40 + ks * 16 + kg * 8);
                    acc[mf] = mfma16(afr, bfr, acc[mf]);
                }
            }
        }
    }
    int oc = n0 + wn * 32 + l31;
    float bb = bias[oc];
    #pragma unroll
    for (int mf = 0; mf < 4; mf++) {
        #pragma unroll
        for (int reg = 0; reg < 16; reg++) {
            int row = (reg & 3) + 8 * (reg >> 2) + 4 * kg;
            int p = wm * 128 + mf * 32 + row;
            int y = ty0 + (p >> 4), x = tx0 + (p & 15);
            float v = acc[mf][reg] + bb;
            v = v / (1.f + expf(-v));
            out[((size_t)(b * HW + y * W_ + x)) * OC + oc] = f2bf(v);
        }
    }
}

// ---------------------------------------------------------------------------
// Snake-conv GEMM with fused bilinear gather AND fused GN-stats reduction.
// Epilogue atomically accumulates per-(b,channel) sum/sumsq into stat
// [morph][B][OC][2] (fp32, pre-zeroed).  grid (400, OC/128, 2)
// ---------------------------------------------------------------------------
__global__ __launch_bounds__(256, 4) void dsc_gemm_kernel(
    const ushort* __restrict__ xh, const float* __restrict__ off4,
    const ushort* __restrict__ Bwx, const float* __restrict__ biasx,
    ushort* __restrict__ outx,
    const ushort* __restrict__ Bwy, const float* __restrict__ biasy,
    ushort* __restrict__ outy, float* __restrict__ stat, int CIN, int OC) {
    __shared__ ushort s_a[128 * 64];
    __shared__ ushort s_b[128 * 64];
    __shared__ int   s_i0[3][128];
    __shared__ int   s_i1[3][128];
    __shared__ float s_wl[3][128];
    int tid = threadIdx.x;
    int morph = blockIdx.z;
    const ushort* Bw = morph ? Bwy : Bwx;
    const float* bias = morph ? biasy : biasx;
    ushort* out = morph ? outy : outx;
    float* statm = stat + (size_t)morph * B_ * 256 * 2;
    int m0 = blockIdx.x * 128, n0 = blockIdx.y * 128;
    int b = m0 / HW, hw0 = m0 - b * HW;    // 6400 % 128 == 0
    for (int u = tid; u < 384; u += 256) {
        int k3 = u >> 7, r = u & 127;
        int hw = hw0 + r;
        int h = hw / W_, w = hw - h * W_;
        float bend = 0.f;
        if (k3 != 1) {
            int mp = (morph ? 2 : 0) + (k3 >> 1);
            bend = off4[((size_t)b * 4 + mp) * HW + hw];
        }
        int i0, i1; float wl;
        if (morph == 0) {
            float ys = fminf(fmaxf((float)h + bend, 0.f), 79.f);
            float y0f = floorf(ys); wl = ys - y0f;
            int y0 = (int)y0f, y1 = min(y0 + 1, 79);
            int xk = min(max(w + k3 - 1, 0), 79);
            i0 = y0 * W_ + xk; i1 = y1 * W_ + xk;
        } else {
            float xs = fminf(fmaxf((float)w + bend, 0.f), 79.f);
            float x0f = floorf(xs); wl = xs - x0f;
            int x0 = (int)x0f, x1 = min(x0 + 1, 79);
            int yk = min(max(h + k3 - 1, 0), 79);
            i0 = yk * W_ + x0; i1 = yk * W_ + x1;
        }
        s_i0[k3][r] = i0; s_i1[k3][r] = i1; s_wl[k3][r] = wl;
    }
    int lane = tid & 63, wid = tid >> 6;
    int l31 = lane & 31, kg = lane >> 5;
    int wm = wid >> 1, wn = wid & 1;
    f32x16 acc[2][2] = {};
    int K = 3 * CIN, nk = K >> 6;
    const ushort* xb = xh + (size_t)b * HW * CIN;
    for (int kc = 0; kc < nk; kc++) {
        int kg64 = kc << 6;
        int k3 = kg64 / CIN;              // uniform per kc (64 | CIN)
        int cioff = kg64 - k3 * CIN;
        __syncthreads();
        // B: async DMA, 16 wave-calls
        #pragma unroll
        for (int j = 0; j < 4; j++) {
            int s = (wid * 4 + j) * 64 + lane;
            int r = s >> 3, c8p = s & 7;
            int c8l = c8p ^ (r & 7);
            async16(Bw + (size_t)(n0 + r) * K + kg64 + c8l * 8, s_b + s * 8);
        }
        // A: gather + lerp (VGPR), swizzled write
        #pragma unroll
        for (int i = 0; i < 4; i++) {
            int s = i * 256 + tid;
            int r = s >> 3, c8p = s & 7;
            int c8l = c8p ^ (r & 7);
            int ci = cioff + c8l * 8;
            float wl = s_wl[k3][r];
            uint4 u0 = *(const uint4*)(xb + (size_t)s_i0[k3][r] * CIN + ci);
            uint4 u1 = *(const uint4*)(xb + (size_t)s_i1[k3][r] * CIN + ci);
            const ushort* p0 = (const ushort*)&u0;
            const ushort* p1 = (const ushort*)&u1;
            ushort tv[8];
            #pragma unroll
            for (int j = 0; j < 8; j++) {
                float f0 = bf2f(p0[j]);
                tv[j] = f2bf(f0 + (bf2f(p1[j]) - f0) * wl);
            }
            *(uint4*)(s_a + s * 8) = *(uint4*)tv;
        }
        __syncthreads();
        #pragma unroll
        for (int ks = 0; ks < 4; ks++) {
            int c8l = ks * 2 + kg;
            short8 af0 = *(const short8*)frag_ptr(s_a, wm * 64 + l31, c8l);
            short8 af1 = *(const short8*)frag_ptr(s_a, wm * 64 + 32 + l31, c8l);
            short8 bf0 = *(const short8*)frag_ptr(s_b, wn * 64 + l31, c8l);
            short8 bf1 = *(const short8*)frag_ptr(s_b, wn * 64 + 32 + l31, c8l);
            acc[0][0] = mfma16(af0, bf0, acc[0][0]);
            acc[0][1] = mfma16(af0, bf1, acc[0][1]);
            acc[1][0] = mfma16(af1, bf0, acc[1][0]);
            acc[1][1] = mfma16(af1, bf1, acc[1][1]);
        }
    }
    #pragma unroll
    for (int nf = 0; nf < 2; nf++) {
        int n = n0 + wn * 64 + nf * 32 + l31;
        float bb = bias[n];
        float ssum = 0.f, ssq = 0.f;
        #pragma unroll
        for (int mf = 0; mf < 2; mf++) {
            #pragma unroll
            for (int reg = 0; reg < 16; reg++) {
                int row = (reg & 3) + 8 * (reg >> 2) + 4 * kg;
                int m = m0 + wm * 64 + mf * 32 + row;
                float v = acc[mf][nf][reg] + bb;
                ssum += v; ssq += v * v;
                out[(size_t)m * OC + n] = f2bf(v);
            }
        }
        // combine the two kg-halves (same column, complementary rows)
        ssum += __shfl_xor(ssum, 32);
        ssq  += __shfl_xor(ssq, 32);
        if (kg == 0) {
            float* st = statm + ((size_t)b * OC + n) * 2;
            atomicAdd(st, ssum);
            atomicAdd(st + 1, ssq);
        }
    }
}

// ---------------------------------------------------------------------------
// Pure 128x128 MFMA GEMM over concat-A (up to 3 parts), all staging via
// async global->LDS DMA.  SiLU epilogue.  grid (400, N/128)
// ---------------------------------------------------------------------------
__global__ __launch_bounds__(256, 4) void gemm128_kernel(
    const ushort* __restrict__ a0, const ushort* __restrict__ a1,
    const ushort* __restrict__ a2, int part_k,
    const ushort* __restrict__ Bw, int K, int N,
    const float* __restrict__ bias, ushort* __restrict__ out, int epi_silu) {
    __shared__ ushort s_a[128 * 64];
    __shared__ ushort s_b[128 * 64];
    int tid = threadIdx.x;
    int m0 = blockIdx.x * 128, n0 = blockIdx.y * 128;
    int lane = tid & 63, wid = tid >> 6;
    int l31 = lane & 31, kg = lane >> 5;
    int wm = wid >> 1, wn = wid & 1;
    f32x16 acc[2][2] = {};
    int nk = K >> 6;
    for (int kc = 0; kc < nk; kc++) {
        int kg64 = kc << 6;
        int part = kg64 / part_k;
        int koff = kg64 - part * part_k;
        const ushort* ap = (part == 0) ? a0 : (part == 1 ? a1 : a2);
        __syncthreads();
        #pragma unroll
        for (int j = 0; j < 4; j++) {
            int s = (wid * 4 + j) * 64 + lane;
            int r = s >> 3, c8p = s & 7;
            int c8l = c8p ^ (r & 7);
            async16(ap + (size_t)(m0 + r) * part_k + koff + c8l * 8, s_a + s * 8);
            async16(Bw + (size_t)(n0 + r) * K + kg64 + c8l * 8, s_b + s * 8);
        }
        __syncthreads();
        #pragma unroll
        for (int ks = 0; ks < 4; ks++) {
            int c8l = ks * 2 + kg;
            short8 af0 = *(const short8*)frag_ptr(s_a, wm * 64 + l31, c8l);
            short8 af1 = *(const short8*)frag_ptr(s_a, wm * 64 + 32 + l31, c8l);
            short8 bf0 = *(const short8*)frag_ptr(s_b, wn * 64 + l31, c8l);
            short8 bf1 = *(const short8*)frag_ptr(s_b, wn * 64 + 32 + l31, c8l);
            acc[0][0] = mfma16(af0, bf0, acc[0][0]);
            acc[0][1] = mfma16(af0, bf1, acc[0][1]);
            acc[1][0] = mfma16(af1, bf0, acc[1][0]);
            acc[1][1] = mfma16(af1, bf1, acc[1][1]);
        }
    }
    #pragma unroll
    for (int nf = 0; nf < 2; nf++) {
        int n = n0 + wn * 64 + nf * 32 + l31;
        float bb = bias[n];
        #pragma unroll
        for (int mf = 0; mf < 2; mf++) {
            #pragma unroll
            for (int reg = 0; reg < 16; reg++) {
                int row = (reg & 3) + 8 * (reg >> 2) + 4 * kg;
                int m = m0 + wm * 64 + mf * 32 + row;
                float v = acc[mf][nf][reg] + bb;
                if (epi_silu) v = v / (1.f + expf(-v));
                out[(size_t)m * N + n] = f2bf(v);
            }
        }
    }
}

// ---------------------------------------------------------------------------
// GN finalize from fused per-channel sums: grid (ceil(B*C/256), 2)
// stat layout [which][B][256-stride? no: B*C*2 packed at which*B_*256*2]
// ---------------------------------------------------------------------------
__global__ void gn_finalize_kernel(const float* __restrict__ stat,
                                   const float* __restrict__ gx,
                                   const float* __restrict__ bx,
                                   const float* __restrict__ gy,
                                   const float* __restrict__ by,
                                   float* __restrict__ scx, float* __restrict__ shx,
                                   float* __restrict__ scy, float* __restrict__ shy,
                                   int C) {
    int idx = blockIdx.x * 256 + threadIdx.x;
    if (idx >= B_ * C) return;
    int which = blockIdx.y;
    const float* gamma = which ? gy : gx;
    const float* beta  = which ? by : bx;
    float* sc = which ? scy : scx;
    float* sh = which ? shy : shx;
    int b = idx / C, c = idx - b * C;
    const float* st = stat + (size_t)which * B_ * 256 * 2
                    + ((size_t)b * C + (c & ~3)) * 2;
    float s  = st[0] + st[2] + st[4] + st[6];
    float sq = st[1] + st[3] + st[5] + st[7];
    float mean = s / (4.f * HW);
    float var = sq / (4.f * HW) - mean * mean;
    float rs = rsqrtf(var + 1e-5f);
    float scale = rs * gamma[c];
    sc[idx] = scale;
    sh[idx] = beta[c] - mean * scale;
}

// ---------------------------------------------------------------------------
// GN apply + ReLU, in place on bf16 NHWC.  grid (B*HW*C/2048, 2)
// ---------------------------------------------------------------------------
__global__ __launch_bounds__(256) void gn_apply_kernel(
    ushort* __restrict__ bqx, ushort* __restrict__ bqy,
    const float* __restrict__ scx, const float* __restrict__ shx,
    const float* __restrict__ scy, const float* __restrict__ shy, int C) {
    ushort* bq = blockIdx.y ? bqy : bqx;
    const float* sc = blockIdx.y ? scy : scx;
    const float* sh = blockIdx.y ? shy : shx;
    size_t e = ((size_t)blockIdx.x * 256 + threadIdx.x) * 8;
    int c = (int)(e % C);
    int b = (int)(e / ((size_t)HW * C));
    const float* scb = sc + (size_t)b * C + c;
    const float* shb = sh + (size_t)b * C + c;
    uint4 v = *(const uint4*)(bq + e);
    const ushort* sv = (const ushort*)&v;
    ushort tv[8];
    #pragma unroll
    for (int j = 0; j < 8; j++)
        tv[j] = f2bf(fmaxf(bf2f(sv[j]) * scb[j] + shb[j], 0.f));
    *(uint4*)(bq + e) = *(uint4*)tv;
}

// ---------------------------------------------------------------------------
// Host orchestration
// ---------------------------------------------------------------------------
struct BlkBuf {
    ushort *xh, *abuf, *bqx, *bqy, *hout;
    float *off4, *stat, *scx, *shx, *scy, *shy, *boff;
    ushort *wc, *wdx, *wdy, *wf, *woff;
};

static void run_block(const BlkBuf& B, int CIN, int OC,
                      const float* const* P, hipStream_t stream) {
    dim3 blk(256);
    hipMemsetAsync(B.stat, 0, (size_t)2 * B_ * 256 * 2 * 4, stream);
    off_conv_mfma_kernel<<<dim3(25, B_), blk, 0, stream>>>(
        B.xh, B.woff, B.boff, B.off4, CIN);
    conv3x3_mfma_kernel<<<dim3(25, OC / 64, B_), blk, 0, stream>>>(
        B.xh, B.wc, P[1], B.abuf, CIN, OC);
    dsc_gemm_kernel<<<dim3(400, OC / 128, 2), blk, 0, stream>>>(
        B.xh, B.off4, B.wdx, P[5], B.bqx, B.wdy, P[11], B.bqy, B.stat, CIN, OC);
    int fgrid = (B_ * OC + 255) / 256;
    gn_finalize_kernel<<<dim3(fgrid, 2), blk, 0, stream>>>(
        B.stat, P[6], P[7], P[12], P[13], B.scx, B.shx, B.scy, B.shy, OC);
    gn_apply_kernel<<<dim3((B_ * HW * OC) / 2048, 2), blk, 0, stream>>>(
        B.bqx, B.bqy, B.scx, B.shx, B.scy, B.shy, OC);
    gemm128_kernel<<<dim3(400, OC / 128), blk, 0, stream>>>(
        B.abuf, B.bqx, B.bqy, OC, B.wf, 3 * OC, OC, P[15], B.hout, 1);
}

extern "C" void kernel_launch(void* const* d_in, const int* in_sizes, int n_in,
                              void* d_out, int out_size, void* d_ws, size_t ws_size,
                              hipStream_t stream) {
    const float* x = (const float*)d_in[0];
    const float* P1[16];
    const float* P2[16];
    for (int i = 0; i < 16; i++) {
        P1[i] = (const float*)d_in[1 + i];
        P2[i] = (const float*)d_in[17 + i];
    }
    char* base = (char*)d_ws;
    size_t off = 0;
    auto alloc = [&](size_t bytes) -> char* {
        off = (off + 255) & ~(size_t)255;
        char* p = base + off;
        off += bytes;
        return p;
    };
    ushort* xh   = (ushort*)alloc((size_t)B_ * HW * 256 * 2);
    ushort* abuf = (ushort*)alloc((size_t)B_ * HW * 256 * 2);
    ushort* bqx  = (ushort*)alloc((size_t)B_ * HW * 256 * 2);
    ushort* bqy  = (ushort*)alloc((size_t)B_ * HW * 256 * 2);
    ushort* h1   = (ushort*)alloc((size_t)B_ * HW * 128 * 2);
    float*  off4 = (float*)alloc((size_t)B_ * 4 * HW * 4);
    float*  stat = (float*)alloc((size_t)2 * B_ * 256 * 2 * 4);
    float*  scx  = (float*)alloc(B_ * 256 * 4);
    float*  shx  = (float*)alloc(B_ * 256 * 4);
    float*  scy  = (float*)alloc(B_ * 256 * 4);
    float*  shy  = (float*)alloc(B_ * 256 * 4);
    ushort* wc1  = (ushort*)alloc((size_t)128 * 9 * 256 * 2);
    ushort* wc2  = (ushort*)alloc((size_t)256 * 9 * 128 * 2);
    ushort* wdx1 = (ushort*)alloc((size_t)128 * 3 * 256 * 2);
    ushort* wdy1 = (ushort*)alloc((size_t)128 * 3 * 256 * 2);
    ushort* wdx2 = (ushort*)alloc((size_t)256 * 3 * 128 * 2);
    ushort* wdy2 = (ushort*)alloc((size_t)256 * 3 * 128 * 2);
    ushort* wf1  = (ushort*)alloc((size_t)128 * 384 * 2);
    ushort* wf2  = (ushort*)alloc((size_t)256 * 768 * 2);
    ushort* wo1  = (ushort*)alloc((size_t)32 * 9 * 256 * 2);
    ushort* wo2  = (ushort*)alloc((size_t)32 * 9 * 128 * 2);
    float*  bo1  = (float*)alloc(32 * 4);
    float*  bo2  = (float*)alloc(32 * 4);

    dim3 blk(256);
    auto wp = [&](const float* s, ushort* d, int OC, int CIN, int T) {
        int n = OC * CIN * T;
        wprep_kernel<<<(n + 255) / 256, blk, 0, stream>>>(s, d, OC, CIN, T);
    };
    wp(P1[0], wc1, 128, 256, 9);
    wp(P1[4], wdx1, 128, 256, 3);
    wp(P1[10], wdy1, 128, 256, 3);
    wp(P1[14], wf1, 128, 384, 1);
    wp(P2[0], wc2, 256, 128, 9);
    wp(P2[4], wdx2, 256, 128, 3);
    wp(P2[10], wdy2, 256, 128, 3);
    wp(P2[14], wf2, 256, 768, 1);
    wprep_off_kernel<<<(32 * 9 * 256 + 255) / 256, blk, 0, stream>>>(
        P1[2], P1[3], P1[8], P1[9], wo1, bo1, 256);
    wprep_off_kernel<<<(32 * 9 * 128 + 255) / 256, blk, 0, stream>>>(
        P2[2], P2[3], P2[8], P2[9], wo2, bo2, 128);

    transpose_x_kernel<<<dim3(100, 4, B_), blk, 0, stream>>>(x, xh, 256);

    BlkBuf B1 = {xh, abuf, bqx, bqy, h1, off4, stat, scx, shx, scy, shy,
                 bo1, wc1, wdx1, wdy1, wf1, wo1};
    run_block(B1, 256, 128, P1, stream);

    ushort* h2 = xh;  // reuse slab (xh dead after block1)
    BlkBuf B2 = {h1, abuf, bqx, bqy, h2, off4, stat, scx, shx, scy, shy,
                 bo2, wc2, wdx2, wdy2, wf2, wo2};
    run_block(B2, 128, 256, P2, stream);

    final_add_kernel<<<dim3(100, 4, B_), blk, 0, stream>>>(x, h2, (float*)d_out, 256);
}

// Round 7
// 581.946 us; speedup vs baseline: 7.6326x; 1.0028x over previous
//
#include <hip/hip_runtime.h>
#include <cstddef>

#define B_   8
#define H_   80
#define W_   80
#define HW   6400

typedef __attribute__((ext_vector_type(8)))  short short8;
typedef __attribute__((ext_vector_type(16))) float f32x16;

__device__ __forceinline__ float bf2f(ushort u) {
    return __uint_as_float(((unsigned)u) << 16);
}
__device__ __forceinline__ ushort f2bf(float f) {
    unsigned u = __float_as_uint(f);
    u += 0x7FFF + ((u >> 16) & 1);   // RNE
    return (ushort)(u >> 16);
}
__device__ __forceinline__ f32x16 mfma16(short8 a, short8 b, f32x16 c) {
    return __builtin_amdgcn_mfma_f32_32x32x16_bf16(a, b, c, 0, 0, 0);
}
// async global->LDS, 16B per lane (wave-uniform base + lane*16)
__device__ __forceinline__ void async16(const void* g, void* l) {
    __builtin_amdgcn_global_load_lds(
        (const __attribute__((address_space(1))) unsigned int*)g,
        (__attribute__((address_space(3))) unsigned int*)l, 16, 0, 0);
}
// swizzled fragment address in 64-ushort-stride LDS tile
__device__ __forceinline__ const ushort* frag_ptr(const ushort* sbuf, int row, int c8l) {
    return sbuf + row * 64 + ((c8l ^ (row & 7)) << 3);
}

// ---------------------------------------------------------------------------
// x fp32 NCHW -> xh bf16 NHWC.  grid (HW/64, C/64, B)
// ---------------------------------------------------------------------------
__global__ __launch_bounds__(256) void transpose_x_kernel(
    const float* __restrict__ x, ushort* __restrict__ xh, int C) {
    __shared__ float s[64][65];
    int hw0 = blockIdx.x * 64, c0 = blockIdx.y * 64, b = blockIdx.z;
    int t = threadIdx.x;
    int hl = t & 63, cq = t >> 6;
    #pragma unroll
    for (int i = 0; i < 16; i++) {
        int cl = cq * 16 + i;
        s[cl][hl] = x[((size_t)(b * C + c0 + cl)) * HW + hw0 + hl];
    }
    __syncthreads();
    int cl = t & 63, hq = t >> 6;
    #pragma unroll
    for (int i = 0; i < 16; i++) {
        int hl2 = hq * 16 + i;
        xh[((size_t)(b * HW + hw0 + hl2)) * C + c0 + cl] = f2bf(s[cl][hl2]);
    }
}

// ---------------------------------------------------------------------------
// final: d_out[b][c][hw] = x[b][c][hw] + h2[b][hw][c]
// ---------------------------------------------------------------------------
__global__ __launch_bounds__(256) void final_add_kernel(
    const float* __restrict__ x, const ushort* __restrict__ h2,
    float* __restrict__ out, int C) {
    __shared__ float s[64][65];
    int hw0 = blockIdx.x * 64, c0 = blockIdx.y * 64, b = blockIdx.z;
    int t = threadIdx.x;
    int cl = t & 63, hq = t >> 6;
    #pragma unroll
    for (int i = 0; i < 16; i++) {
        int hl = hq * 16 + i;
        s[cl][hl] = bf2f(h2[((size_t)(b * HW + hw0 + hl)) * C + c0 + cl]);
    }
    __syncthreads();
    int hl = t & 63, cq = t >> 6;
    #pragma unroll
    for (int i = 0; i < 16; i++) {
        int cl2 = cq * 16 + i;
        size_t o = ((size_t)(b * C + c0 + cl2)) * HW + hw0 + hl;
        out[o] = x[o] + s[cl2][hl];
    }
}

// ---------------------------------------------------------------------------
// Weight prep: src fp32 [OC][CIN][T] -> dst bf16 [OC][T][CIN]
// ---------------------------------------------------------------------------
__global__ void wprep_kernel(const float* __restrict__ src,
                             ushort* __restrict__ dst, int OC, int CIN, int T) {
    int idx = blockIdx.x * 256 + threadIdx.x;
    if (idx >= OC * CIN * T) return;
    int oc = idx / (CIN * T);
    int r = idx - oc * CIN * T;
    int ci = r / T, t_ = r - ci * T;
    dst[((size_t)oc * T + t_) * CIN + ci] = f2bf(src[idx]);
}

// ---------------------------------------------------------------------------
// Offset weight prep: pack 4 wanted channels (+28 zero pads) into [32][9][CIN]
// ---------------------------------------------------------------------------
__global__ void wprep_off_kernel(const float* __restrict__ wx_,
                                 const float* __restrict__ bx_,
                                 const float* __restrict__ wy_,
                                 const float* __restrict__ by_,
                                 ushort* __restrict__ dst,
                                 float* __restrict__ bdst, int CIN) {
    int idx = blockIdx.x * 256 + threadIdx.x;
    if (idx < 4) {
        const int chs[4] = {0, 2, 3, 5};
        bdst[idx] = (idx < 2) ? bx_[chs[idx]] : by_[chs[idx]];
    }
    if (idx >= 32 * 9 * CIN) return;
    int oc = idx / (9 * CIN);
    int r = idx - oc * 9 * CIN;
    int tap = r / CIN, ci = r - tap * CIN;
    float v = 0.f;
    if (oc < 4) {
        const int chs[4] = {0, 2, 3, 5};
        const float* src = (oc < 2) ? wx_ : wy_;
        v = src[((size_t)chs[oc] * CIN + ci) * 9 + tap];
    }
    dst[idx] = f2bf(v);
}

// ---------------------------------------------------------------------------
// Offset conv via MFMA: 16x16 spatial tile, N=32 (4 real oc), tanh epilogue.
// Conflict-free LDS: 128B rows (2 px / 2 oc per row) + 8-slot XOR swizzle.
// grid (25, B)
// ---------------------------------------------------------------------------
__global__ __launch_bounds__(256, 2) void off_conv_mfma_kernel(
    const ushort* __restrict__ xh, const ushort* __restrict__ wB,
    const float* __restrict__ bias, float* __restrict__ off4, int CIN) {
    __shared__ ushort s_x[162 * 64];   // row = pid>>1, slot = (pid&1)*4+ci8 ^ row&7
    __shared__ ushort s_w[144 * 64];   // row = tap*16+(oc>>1), slot = (oc&1)*4+ci8 ^ row&7
    int tid = threadIdx.x;
    int ty0 = (blockIdx.x / 5) * 16, tx0 = (blockIdx.x % 5) * 16;
    int b = blockIdx.y;
    int lane = tid & 63, wid = tid >> 6;
    int l31 = lane & 31, kg = lane >> 5;
    int pym[2], pxm[2];
    #pragma unroll
    for (int mf = 0; mf < 2; mf++) {
        int p = wid * 64 + mf * 32 + l31;
        pym[mf] = p >> 4; pxm[mf] = p & 15;
    }
    f32x16 acc[2] = {};
    for (int c0 = 0; c0 < CIN; c0 += 32) {
        __syncthreads();
        for (int u = tid; u < 1296; u += 256) {
            int pid = u >> 2, ci8 = u & 3;
            int r = pid / 18, c = pid - r * 18;
            int gy = ty0 + r - 1, gx = tx0 + c - 1;
            uint4 v = make_uint4(0, 0, 0, 0);
            if ((unsigned)gy < H_ && (unsigned)gx < W_)
                v = *(const uint4*)(xh + ((size_t)(b * HW + gy * W_ + gx)) * CIN + c0 + ci8 * 8);
            int row = pid >> 1;
            int phys = (((pid & 1) << 2) + ci8) ^ (row & 7);
            *(uint4*)(s_x + row * 64 + phys * 8) = v;
        }
        // weights via async DMA: 1152 16B-slots, 18 wave-calls
        for (int cc = wid; cc < 18; cc += 4) {
            int L = cc * 64 + lane;
            int row = L >> 3, phys = L & 7;
            int logical = phys ^ (row & 7);
            int tap = row >> 4, ocp = row & 15;
            int oc = ocp * 2 + (logical >> 2), ci8 = logical & 3;
            async16(wB + ((size_t)oc * 9 + tap) * CIN + c0 + ci8 * 8,
                    s_w + (size_t)L * 8);
        }
        __syncthreads();
        #pragma unroll
        for (int tap = 0; tap < 9; tap++) {
            int dy = tap / 3, dx = tap - dy * 3;
            int wrow = tap * 16 + (l31 >> 1);
            #pragma unroll
            for (int ks = 0; ks < 2; ks++) {
                int blk = ks * 2 + kg;
                int wphys = (((l31 & 1) << 2) + blk) ^ (wrow & 7);
                short8 bfr = *(const short8*)(s_w + wrow * 64 + wphys * 8);
                #pragma unroll
                for (int mf = 0; mf < 2; mf++) {
                    int pix = (pym[mf] + dy) * 18 + (pxm[mf] + dx);
                    int xrow = pix >> 1;
                    int xphys = (((pix & 1) << 2) + blk) ^ (xrow & 7);
                    short8 afr = *(const short8*)(s_x + xrow * 64 + xphys * 8);
                    acc[mf] = mfma16(afr, bfr, acc[mf]);
                }
            }
        }
    }
    int oc = l31;
    if (oc < 4) {
        float bb = bias[oc];
        #pragma unroll
        for (int mf = 0; mf < 2; mf++) {
            #pragma unroll
            for (int reg = 0; reg < 16; reg++) {
                int row = (reg & 3) + 8 * (reg >> 2) + 4 * kg;
                int p = wid * 64 + mf * 32 + row;
                int y = ty0 + (p >> 4), x = tx0 + (p & 15);
                off4[((size_t)b * 4 + oc) * HW + y * W_ + x] = tanhf(acc[mf][reg] + bb);
            }
        }
    }
}

// ---------------------------------------------------------------------------
// Implicit conv3x3 + bias + SiLU via MFMA.  16x16 tile, BN=64 oc.
// Conflict-free LDS: 128B rows + 8-slot XOR swizzle (gemm128-proven pattern).
// grid (25, OC/64, B)
// ---------------------------------------------------------------------------
__global__ __launch_bounds__(256, 2) void conv3x3_mfma_kernel(
    const ushort* __restrict__ xh, const ushort* __restrict__ wB,
    const float* __restrict__ bias, ushort* __restrict__ out,
    int CIN, int OC) {
    __shared__ ushort s_x[162 * 64];   // row = pid>>1
    __shared__ ushort s_w[288 * 64];   // row = tap*32 + (oc>>1)
    int tid = threadIdx.x;
    int ty0 = (blockIdx.x / 5) * 16, tx0 = (blockIdx.x % 5) * 16;
    int n0 = blockIdx.y * 64, b = blockIdx.z;
    int lane = tid & 63, wid = tid >> 6;
    int l31 = lane & 31, kg = lane >> 5;
    int wm = wid >> 1, wn = wid & 1;
    int pym[4], pxm[4];
    #pragma unroll
    for (int mf = 0; mf < 4; mf++) {
        int p = wm * 128 + mf * 32 + l31;
        pym[mf] = p >> 4; pxm[mf] = p & 15;
    }
    f32x16 acc[4] = {};
    for (int c0 = 0; c0 < CIN; c0 += 32) {
        __syncthreads();
        for (int u = tid; u < 1296; u += 256) {
            int pid = u >> 2, ci8 = u & 3;
            int r = pid / 18, c = pid - r * 18;
            int gy = ty0 + r - 1, gx = tx0 + c - 1;
            uint4 v = make_uint4(0, 0, 0, 0);
            if ((unsigned)gy < H_ && (unsigned)gx < W_)
                v = *(const uint4*)(xh + ((size_t)(b * HW + gy * W_ + gx)) * CIN + c0 + ci8 * 8);
            int row = pid >> 1;
            int phys = (((pid & 1) << 2) + ci8) ^ (row & 7);
            *(uint4*)(s_x + row * 64 + phys * 8) = v;
        }
        // weights: 2304 16B-slots = 36 wave-calls (9 per wave)
        #pragma unroll
        for (int j = 0; j < 9; j++) {
            int L = (wid * 9 + j) * 64 + lane;
            int row = L >> 3, phys = L & 7;
            int logical = phys ^ (row & 7);
            int tap = row >> 5, ocp = row & 31;
            int oc = ocp * 2 + (logical >> 2), ci8 = logical & 3;
            async16(wB + ((size_t)(n0 + oc) * 9 + tap) * CIN + c0 + ci8 * 8,
                    s_w + (size_t)L * 8);
        }
        __syncthreads();
        #pragma unroll
        for (int tap = 0; tap < 9; tap++) {
            int dy = tap / 3, dx = tap - dy * 3;
            int ocl = wn * 32 + l31;
            int wrow = tap * 32 + (ocl >> 1);
            #pragma unroll
            for (int ks = 0; ks < 2; ks++) {
                int blk = ks * 2 + kg;
                int wphys = (((ocl & 1) << 2) + blk) ^ (wrow & 7);
                short8 bfr = *(const short8*)(s_w + wrow * 64 + wphys * 8);
                #pragma unroll
                for (int mf = 0; mf < 4; mf++) {
                    int pix = (pym[mf] + dy) * 18 + (pxm[mf] + dx);
                    int xrow = pix >> 1;
                    int xphys = (((pix & 1) << 2) + blk) ^ (xrow & 7);
                    short8 afr = *(const short8*)(s_x + xrow * 64 + xphys * 8);
                    acc[mf] = mfma16(afr, bfr, acc[mf]);
                }
            }
        }
    }
    int oc = n0 + wn * 32 + l31;
    float bb = bias[oc];
    #pragma unroll
    for (int mf = 0; mf < 4; mf++) {
        #pragma unroll
        for (int reg = 0; reg < 16; reg++) {
            int row = (reg & 3) + 8 * (reg >> 2) + 4 * kg;
            int p = wm * 128 + mf * 32 + row;
            int y = ty0 + (p >> 4), x = tx0 + (p & 15);
            float v = acc[mf][reg] + bb;
            v = v / (1.f + expf(-v));
            out[((size_t)(b * HW + y * W_ + x)) * OC + oc] = f2bf(v);
        }
    }
}

// ---------------------------------------------------------------------------
// Snake-conv GEMM with fused bilinear gather AND fused GN-stats reduction.
// Epilogue atomically accumulates per-(b,channel) sum/sumsq into stat
// [morph][B][OC][2] (fp32, pre-zeroed).  grid (400, OC/128, 2)
// ---------------------------------------------------------------------------
__global__ __launch_bounds__(256, 4) void dsc_gemm_kernel(
    const ushort* __restrict__ xh, const float* __restrict__ off4,
    const ushort* __restrict__ Bwx, const float* __restrict__ biasx,
    ushort* __restrict__ outx,
    const ushort* __restrict__ Bwy, const float* __restrict__ biasy,
    ushort* __restrict__ outy, float* __restrict__ stat, int CIN, int OC) {
    __shared__ ushort s_a[128 * 64];
    __shared__ ushort s_b[128 * 64];
    __shared__ int   s_i0[3][128];
    __shared__ int   s_i1[3][128];
    __shared__ float s_wl[3][128];
    int tid = threadIdx.x;
    int morph = blockIdx.z;
    const ushort* Bw = morph ? Bwy : Bwx;
    const float* bias = morph ? biasy : biasx;
    ushort* out = morph ? outy : outx;
    float* statm = stat + (size_t)morph * B_ * 256 * 2;
    int m0 = blockIdx.x * 128, n0 = blockIdx.y * 128;
    int b = m0 / HW, hw0 = m0 - b * HW;    // 6400 % 128 == 0
    for (int u = tid; u < 384; u += 256) {
        int k3 = u >> 7, r = u & 127;
        int hw = hw0 + r;
        int h = hw / W_, w = hw - h * W_;
        float bend = 0.f;
        if (k3 != 1) {
            int mp = (morph ? 2 : 0) + (k3 >> 1);
            bend = off4[((size_t)b * 4 + mp) * HW + hw];
        }
        int i0, i1; float wl;
        if (morph == 0) {
            float ys = fminf(fmaxf((float)h + bend, 0.f), 79.f);
            float y0f = floorf(ys); wl = ys - y0f;
            int y0 = (int)y0f, y1 = min(y0 + 1, 79);
            int xk = min(max(w + k3 - 1, 0), 79);
            i0 = y0 * W_ + xk; i1 = y1 * W_ + xk;
        } else {
            float xs = fminf(fmaxf((float)w + bend, 0.f), 79.f);
            float x0f = floorf(xs); wl = xs - x0f;
            int x0 = (int)x0f, x1 = min(x0 + 1, 79);
            int yk = min(max(h + k3 - 1, 0), 79);
            i0 = yk * W_ + x0; i1 = yk * W_ + x1;
        }
        s_i0[k3][r] = i0; s_i1[k3][r] = i1; s_wl[k3][r] = wl;
    }
    int lane = tid & 63, wid = tid >> 6;
    int l31 = lane & 31, kg = lane >> 5;
    int wm = wid >> 1, wn = wid & 1;
    f32x16 acc[2][2] = {};
    int K = 3 * CIN, nk = K >> 6;
    const ushort* xb = xh + (size_t)b * HW * CIN;
    for (int kc = 0; kc < nk; kc++) {
        int kg64 = kc << 6;
        int k3 = kg64 / CIN;              // uniform per kc (64 | CIN)
        int cioff = kg64 - k3 * CIN;
        __syncthreads();
        // B: async DMA, 16 wave-calls
        #pragma unroll
        for (int j = 0; j < 4; j++) {
            int s = (wid * 4 + j) * 64 + lane;
            int r = s >> 3, c8p = s & 7;
            int c8l = c8p ^ (r & 7);
            async16(Bw + (size_t)(n0 + r) * K + kg64 + c8l * 8, s_b + s * 8);
        }
        // A: gather + lerp (VGPR), swizzled write
        #pragma unroll
        for (int i = 0; i < 4; i++) {
            int s = i * 256 + tid;
            int r = s >> 3, c8p = s & 7;
            int c8l = c8p ^ (r & 7);
            int ci = cioff + c8l * 8;
            float wl = s_wl[k3][r];
            uint4 u0 = *(const uint4*)(xb + (size_t)s_i0[k3][r] * CIN + ci);
            uint4 u1 = *(const uint4*)(xb + (size_t)s_i1[k3][r] * CIN + ci);
            const ushort* p0 = (const ushort*)&u0;
            const ushort* p1 = (const ushort*)&u1;
            ushort tv[8];
            #pragma unroll
            for (int j = 0; j < 8; j++) {
                float f0 = bf2f(p0[j]);
                tv[j] = f2bf(f0 + (bf2f(p1[j]) - f0) * wl);
            }
            *(uint4*)(s_a + s * 8) = *(uint4*)tv;
        }
        __syncthreads();
        #pragma unroll
        for (int ks = 0; ks < 4; ks++) {
            int c8l = ks * 2 + kg;
            short8 af0 = *(const short8*)frag_ptr(s_a, wm * 64 + l31, c8l);
            short8 af1 = *(const short8*)frag_ptr(s_a, wm * 64 + 32 + l31, c8l);
            short8 bf0 = *(const short8*)frag_ptr(s_b, wn * 64 + l31, c8l);
            short8 bf1 = *(const short8*)frag_ptr(s_b, wn * 64 + 32 + l31, c8l);
            acc[0][0] = mfma16(af0, bf0, acc[0][0]);
            acc[0][1] = mfma16(af0, bf1, acc[0][1]);
            acc[1][0] = mfma16(af1, bf0, acc[1][0]);
            acc[1][1] = mfma16(af1, bf1, acc[1][1]);
        }
    }
    #pragma unroll
    for (int nf = 0; nf < 2; nf++) {
        int n = n0 + wn * 64 + nf * 32 + l31;
        float bb = bias[n];
        float ssum = 0.f, ssq = 0.f;
        #pragma unroll
        for (int mf = 0; mf < 2; mf++) {
            #pragma unroll
            for (int reg = 0; reg < 16; reg++) {
                int row = (reg & 3) + 8 * (reg >> 2) + 4 * kg;
                int m = m0 + wm * 64 + mf * 32 + row;
                float v = acc[mf][nf][reg] + bb;
                ssum += v; ssq += v * v;
                out[(size_t)m * OC + n] = f2bf(v);
            }
        }
        // combine the two kg-halves (same column, complementary rows)
        ssum += __shfl_xor(ssum, 32);
        ssq  += __shfl_xor(ssq, 32);
        if (kg == 0) {
            float* st = statm + ((size_t)b * OC + n) * 2;
            atomicAdd(st, ssum);
            atomicAdd(st + 1, ssq);
        }
    }
}

// ---------------------------------------------------------------------------
// Pure 128x128 MFMA GEMM over concat-A (up to 3 parts), all staging via
// async global->LDS DMA.  SiLU epilogue.  grid (400, N/128)
// ---------------------------------------------------------------------------
__global__ __launch_bounds__(256, 4) void gemm128_kernel(
    const ushort* __restrict__ a0, const ushort* __restrict__ a1,
    const ushort* __restrict__ a2, int part_k,
    const ushort* __restrict__ Bw, int K, int N,
    const float* __restrict__ bias, ushort* __restrict__ out, int epi_silu) {
    __shared__ ushort s_a[128 * 64];
    __shared__ ushort s_b[128 * 64];
    int tid = threadIdx.x;
    int m0 = blockIdx.x * 128, n0 = blockIdx.y * 128;
    int lane = tid & 63, wid = tid >> 6;
    int l31 = lane & 31, kg = lane >> 5;
    int wm = wid >> 1, wn = wid & 1;
    f32x16 acc[2][2] = {};
    int nk = K >> 6;
    for (int kc = 0; kc < nk; kc++) {
        int kg64 = kc << 6;
        int part = kg64 / part_k;
        int koff = kg64 - part * part_k;
        const ushort* ap = (part == 0) ? a0 : (part == 1 ? a1 : a2);
        __syncthreads();
        #pragma unroll
        for (int j = 0; j < 4; j++) {
            int s = (wid * 4 + j) * 64 + lane;
            int r = s >> 3, c8p = s & 7;
            int c8l = c8p ^ (r & 7);
            async16(ap + (size_t)(m0 + r) * part_k + koff + c8l * 8, s_a + s * 8);
            async16(Bw + (size_t)(n0 + r) * K + kg64 + c8l * 8, s_b + s * 8);
        }
        __syncthreads();
        #pragma unroll
        for (int ks = 0; ks < 4; ks++) {
            int c8l = ks * 2 + kg;
            short8 af0 = *(const short8*)frag_ptr(s_a, wm * 64 + l31, c8l);
            short8 af1 = *(const short8*)frag_ptr(s_a, wm * 64 + 32 + l31, c8l);
            short8 bf0 = *(const short8*)frag_ptr(s_b, wn * 64 + l31, c8l);
            short8 bf1 = *(const short8*)frag_ptr(s_b, wn * 64 + 32 + l31, c8l);
            acc[0][0] = mfma16(af0, bf0, acc[0][0]);
            acc[0][1] = mfma16(af0, bf1, acc[0][1]);
            acc[1][0] = mfma16(af1, bf0, acc[1][0]);
            acc[1][1] = mfma16(af1, bf1, acc[1][1]);
        }
    }
    #pragma unroll
    for (int nf = 0; nf < 2; nf++) {
        int n = n0 + wn * 64 + nf * 32 + l31;
        float bb = bias[n];
        #pragma unroll
        for (int mf = 0; mf < 2; mf++) {
            #pragma unroll
            for (int reg = 0; reg < 16; reg++) {
                int row = (reg & 3) + 8 * (reg >> 2) + 4 * kg;
                int m = m0 + wm * 64 + mf * 32 + row;
                float v = acc[mf][nf][reg] + bb;
                if (epi_silu) v = v / (1.f + expf(-v));
                out[(size_t)m * N + n] = f2bf(v);
            }
        }
    }
}

// ---------------------------------------------------------------------------
// GN finalize from fused per-channel sums: grid (ceil(B*C/256), 2)
// ---------------------------------------------------------------------------
__global__ void gn_finalize_kernel(const float* __restrict__ stat,
                                   const float* __restrict__ gx,
                                   const float* __restrict__ bx,
                                   const float* __restrict__ gy,
                                   const float* __restrict__ by,
                                   float* __restrict__ scx, float* __restrict__ shx,
                                   float* __restrict__ scy, float* __restrict__ shy,
                                   int C) {
    int idx = blockIdx.x * 256 + threadIdx.x;
    if (idx >= B_ * C) return;
    int which = blockIdx.y;
    const float* gamma = which ? gy : gx;
    const float* beta  = which ? by : bx;
    float* sc = which ? scy : scx;
    float* sh = which ? shy : shx;
    int b = idx / C, c = idx - b * C;
    const float* st = stat + (size_t)which * B_ * 256 * 2
                    + ((size_t)b * C + (c & ~3)) * 2;
    float s  = st[0] + st[2] + st[4] + st[6];
    float sq = st[1] + st[3] + st[5] + st[7];
    float mean = s / (4.f * HW);
    float var = sq / (4.f * HW) - mean * mean;
    float rs = rsqrtf(var + 1e-5f);
    float scale = rs * gamma[c];
    sc[idx] = scale;
    sh[idx] = beta[c] - mean * scale;
}

// ---------------------------------------------------------------------------
// GN apply + ReLU, in place on bf16 NHWC.  grid (B*HW*C/2048, 2)
// ---------------------------------------------------------------------------
__global__ __launch_bounds__(256) void gn_apply_kernel(
    ushort* __restrict__ bqx, ushort* __restrict__ bqy,
    const float* __restrict__ scx, const float* __restrict__ shx,
    const float* __restrict__ scy, const float* __restrict__ shy, int C) {
    ushort* bq = blockIdx.y ? bqy : bqx;
    const float* sc = blockIdx.y ? scy : scx;
    const float* sh = blockIdx.y ? shy : shx;
    size_t e = ((size_t)blockIdx.x * 256 + threadIdx.x) * 8;
    int c = (int)(e % C);
    int b = (int)(e / ((size_t)HW * C));
    const float* scb = sc + (size_t)b * C + c;
    const float* shb = sh + (size_t)b * C + c;
    uint4 v = *(const uint4*)(bq + e);
    const ushort* sv = (const ushort*)&v;
    ushort tv[8];
    #pragma unroll
    for (int j = 0; j < 8; j++)
        tv[j] = f2bf(fmaxf(bf2f(sv[j]) * scb[j] + shb[j], 0.f));
    *(uint4*)(bq + e) = *(uint4*)tv;
}

// ---------------------------------------------------------------------------
// Host orchestration
// ---------------------------------------------------------------------------
struct BlkBuf {
    ushort *xh, *abuf, *bqx, *bqy, *hout;
    float *off4, *stat, *scx, *shx, *scy, *shy, *boff;
    ushort *wc, *wdx, *wdy, *wf, *woff;
};

static void run_block(const BlkBuf& B, int CIN, int OC,
                      const float* const* P, hipStream_t stream) {
    dim3 blk(256);
    hipMemsetAsync(B.stat, 0, (size_t)2 * B_ * 256 * 2 * 4, stream);
    off_conv_mfma_kernel<<<dim3(25, B_), blk, 0, stream>>>(
        B.xh, B.woff, B.boff, B.off4, CIN);
    conv3x3_mfma_kernel<<<dim3(25, OC / 64, B_), blk, 0, stream>>>(
        B.xh, B.wc, P[1], B.abuf, CIN, OC);
    dsc_gemm_kernel<<<dim3(400, OC / 128, 2), blk, 0, stream>>>(
        B.xh, B.off4, B.wdx, P[5], B.bqx, B.wdy, P[11], B.bqy, B.stat, CIN, OC);
    int fgrid = (B_ * OC + 255) / 256;
    gn_finalize_kernel<<<dim3(fgrid, 2), blk, 0, stream>>>(
        B.stat, P[6], P[7], P[12], P[13], B.scx, B.shx, B.scy, B.shy, OC);
    gn_apply_kernel<<<dim3((B_ * HW * OC) / 2048, 2), blk, 0, stream>>>(
        B.bqx, B.bqy, B.scx, B.shx, B.scy, B.shy, OC);
    gemm128_kernel<<<dim3(400, OC / 128), blk, 0, stream>>>(
        B.abuf, B.bqx, B.bqy, OC, B.wf, 3 * OC, OC, P[15], B.hout, 1);
}

extern "C" void kernel_launch(void* const* d_in, const int* in_sizes, int n_in,
                              void* d_out, int out_size, void* d_ws, size_t ws_size,
                              hipStream_t stream) {
    const float* x = (const float*)d_in[0];
    const float* P1[16];
    const float* P2[16];
    for (int i = 0; i < 16; i++) {
        P1[i] = (const float*)d_in[1 + i];
        P2[i] = (const float*)d_in[17 + i];
    }
    char* base = (char*)d_ws;
    size_t off = 0;
    auto alloc = [&](size_t bytes) -> char* {
        off = (off + 255) & ~(size_t)255;
        char* p = base + off;
        off += bytes;
        return p;
    };
    ushort* xh   = (ushort*)alloc((size_t)B_ * HW * 256 * 2);
    ushort* abuf = (ushort*)alloc((size_t)B_ * HW * 256 * 2);
    ushort* bqx  = (ushort*)alloc((size_t)B_ * HW * 256 * 2);
    ushort* bqy  = (ushort*)alloc((size_t)B_ * HW * 256 * 2);
    ushort* h1   = (ushort*)alloc((size_t)B_ * HW * 128 * 2);
    float*  off4 = (float*)alloc((size_t)B_ * 4 * HW * 4);
    float*  stat = (float*)alloc((size_t)2 * B_ * 256 * 2 * 4);
    float*  scx  = (float*)alloc(B_ * 256 * 4);
    float*  shx  = (float*)alloc(B_ * 256 * 4);
    float*  scy  = (float*)alloc(B_ * 256 * 4);
    float*  shy  = (float*)alloc(B_ * 256 * 4);
    ushort* wc1  = (ushort*)alloc((size_t)128 * 9 * 256 * 2);
    ushort* wc2  = (ushort*)alloc((size_t)256 * 9 * 128 * 2);
    ushort* wdx1 = (ushort*)alloc((size_t)128 * 3 * 256 * 2);
    ushort* wdy1 = (ushort*)alloc((size_t)128 * 3 * 256 * 2);
    ushort* wdx2 = (ushort*)alloc((size_t)256 * 3 * 128 * 2);
    ushort* wdy2 = (ushort*)alloc((size_t)256 * 3 * 128 * 2);
    ushort* wf1  = (ushort*)alloc((size_t)128 * 384 * 2);
    ushort* wf2  = (ushort*)alloc((size_t)256 * 768 * 2);
    ushort* wo1  = (ushort*)alloc((size_t)32 * 9 * 256 * 2);
    ushort* wo2  = (ushort*)alloc((size_t)32 * 9 * 128 * 2);
    float*  bo1  = (float*)alloc(32 * 4);
    float*  bo2  = (float*)alloc(32 * 4);

    dim3 blk(256);
    auto wp = [&](const float* s, ushort* d, int OC, int CIN, int T) {
        int n = OC * CIN * T;
        wprep_kernel<<<(n + 255) / 256, blk, 0, stream>>>(s, d, OC, CIN, T);
    };
    wp(P1[0], wc1, 128, 256, 9);
    wp(P1[4], wdx1, 128, 256, 3);
    wp(P1[10], wdy1, 128, 256, 3);
    wp(P1[14], wf1, 128, 384, 1);
    wp(P2[0], wc2, 256, 128, 9);
    wp(P2[4], wdx2, 256, 128, 3);
    wp(P2[10], wdy2, 256, 128, 3);
    wp(P2[14], wf2, 256, 768, 1);
    wprep_off_kernel<<<(32 * 9 * 256 + 255) / 256, blk, 0, stream>>>(
        P1[2], P1[3], P1[8], P1[9], wo1, bo1, 256);
    wprep_off_kernel<<<(32 * 9 * 128 + 255) / 256, blk, 0, stream>>>(
        P2[2], P2[3], P2[8], P2[9], wo2, bo2, 128);

    transpose_x_kernel<<<dim3(100, 4, B_), blk, 0, stream>>>(x, xh, 256);

    BlkBuf B1 = {xh, abuf, bqx, bqy, h1, off4, stat, scx, shx, scy, shy,
                 bo1, wc1, wdx1, wdy1, wf1, wo1};
    run_block(B1, 256, 128, P1, stream);

    ushort* h2 = xh;  // reuse slab (xh dead after block1)
    BlkBuf B2 = {h1, abuf, bqx, bqy, h2, off4, stat, scx, shx, scy, shy,
                 bo2, wc2, wdx2, wdy2, wf2, wo2};
    run_block(B2, 128, 256, P2, stream);

    final_add_kernel<<<dim3(100, 4, B_), blk, 0, stream>>>(x, h2, (float*)d_out, 256);
}